// Round 6
// baseline (784.947 us; speedup 1.0000x reference)
//
#include <hip/hip_runtime.h>
#include <hip/hip_bf16.h>

typedef _Float16 half2v __attribute__((ext_vector_type(2)));
typedef unsigned int u32;

// single-instruction packed f16 dot with f32 accumulate
__device__ __forceinline__ float dot2(u32 a, u32 b, float c) {
  float d;
  asm("v_dot2_f32_f16 %0, %1, %2, %3" : "=v"(d) : "v"(a), "v"(b), "v"(c));
  return d;
}

// pack two f32 -> f16x2, as u32
__device__ __forceinline__ u32 pkrtz(float a, float b) {
  return __builtin_bit_cast(u32, __builtin_amdgcn_cvt_pkrtz(a, b));
}

__device__ __forceinline__ u32 pack_relu(float a, float b) {
  return pkrtz(fmaxf(a, 0.0f), fmaxf(b, 0.0f));
}

__device__ __forceinline__ u32 max2(u32 a, u32 b) {
  half2v x = __builtin_bit_cast(half2v, a);
  half2v y = __builtin_bit_cast(half2v, b);
  x.x = (y.x > x.x) ? y.x : x.x;
  x.y = (y.y > x.y) ? y.y : x.y;
  return __builtin_bit_cast(u32, x);
}

__device__ __forceinline__ int imin(int a, int b) { return a < b ? a : b; }

// ---- packed weight layout in d_ws (u32 = one half2 pair) ---------------
#define W2P 0       // [2][5][5kx][8co]          = 400
#define W3P 400     // [4][3][32: kx*10+co pad]  = 384
#define W4P 784     // [5][3][3kx][16co]         = 720
#define W5P 1504    // [8][3][3kx][24co]         = 1728
#define WDP 3232    // [10][108]                 = 1080
#define WTOT 4312

__global__ void __launch_bounds__(256) prep_weights(
    const float* __restrict__ w2, const float* __restrict__ w3,
    const float* __restrict__ w4, const float* __restrict__ w5,
    const float* __restrict__ wd, u32* __restrict__ wp) {
  int i = threadIdx.x + blockIdx.x * 256;
  if (i < 400) {  // w2: src [8][3][5][5]
    int co = i & 7, r = i >> 3;
    int kx = r % 5, ky = (r / 5) % 5, cp = r / 25;
    int s = ky * 5 + kx;
    float lo = w2[co * 75 + (2 * cp) * 25 + s];
    float hi = (2 * cp + 1 < 3) ? w2[co * 75 + (2 * cp + 1) * 25 + s] : 0.0f;
    wp[W2P + i] = pkrtz(lo, hi);
  } else if (i < 784) {  // w3: src [10][8][3][3]
    int j = i - 400;
    int b = j >> 5, e = j & 31;
    int cp = b / 3, ky = b % 3;
    u32 v = 0;
    if (e < 30) {
      int kx = e / 10, co = e % 10, s = ky * 3 + kx;
      v = pkrtz(w3[co * 72 + (2 * cp) * 9 + s], w3[co * 72 + (2 * cp + 1) * 9 + s]);
    }
    wp[W3P + j] = v;
  } else if (i < 1504) {  // w4: src [16][10][3][3]
    int j = i - 784;
    int co = j & 15, r = j >> 4;
    int kx = r % 3, ky = (r / 3) % 3, cp = r / 9;
    int s = ky * 3 + kx;
    wp[W4P + j] = pkrtz(w4[co * 90 + (2 * cp) * 9 + s], w4[co * 90 + (2 * cp + 1) * 9 + s]);
  } else if (i < 3232) {  // w5: src [24][16][3][3]
    int j = i - 1504;
    int co = j % 24, r = j / 24;
    int kx = r % 3, ky = (r / 3) % 3, cp = r / 9;
    int s = ky * 3 + kx;
    wp[W5P + j] = pkrtz(w5[co * 144 + (2 * cp) * 9 + s], w5[co * 144 + (2 * cp + 1) * 9 + s]);
  } else if (i < WTOT) {  // wd: src [10][216], k = ci*9 + s
    int j = i - 3232;
    int o = j / 108, r = j % 108, cp = r / 9, s = r % 9;
    wp[WDP + j] = pkrtz(wd[o * 216 + (2 * cp) * 9 + s], wd[o * 216 + (2 * cp + 1) * 9 + s]);
  }
}

// ---- fused network: 2 images per 256-thread block ----------------------
// Arena A (per img): in_p f32[34][36](1224) -> a2p[4][29][29](3364)
//   -> a3p[5][16][18](1440) -> p2p[8][9][9](648) -> p3(108)+dense partials
// Arena B (per img): a1p[2][32][36](2304) -> p1p[4][16][18](1152)
//   -> a4p[8][15][15](1800) -> a5p[12][7][7](588)
// Strides chosen so quad/pair bases are 16B/8B aligned AND row starts
// rotate across banks (36 = 4 mod 32; 18 staggers odd/even rows).
#define AR_A 3364
#define AR_B 2304
#define AR (AR_A + AR_B)
#define WSOFF (2 * AR)
#define SMEMN (2 * AR + 1728)  // 13064 u32 = 52256 B -> 3 blocks/CU

__global__ void __launch_bounds__(256, 3) mnist_fused(
    const float* __restrict__ in, const float* __restrict__ w1,
    const u32* __restrict__ wp, float* __restrict__ out) {
  __shared__ __align__(16) u32 smem[SMEMN];
  const int t = threadIdx.x;
  const int u = t & 127;
  const int img = t >> 7;
  const long long b = (long long)blockIdx.x * 2 + img;
  u32* SA = smem + img * AR;
  u32* SB = SA + AR_A;
  float* SAf = (float*)SA;
  u32* WS = smem + WSOFF;
  float* WSf = (float*)WS;

  // phase 0: zero in_p + a1p, stage w1 (147 f32)
  for (int i = u; i < 1224; i += 128) SA[i] = 0;
  for (int i = u; i < 2304; i += 128) SB[i] = 0;
  for (int i = t; i < 147; i += 256) WSf[i] = w1[i];
  __syncthreads();

  // stage input (fp32, halo 3, stride 36)
  {
    const float* inb = in + b * 784;
    for (int p = u; p < 784; p += 128) {
      int y = p / 28, x = p % 28;
      SAf[(y + 3) * 36 + (x + 3)] = inb[p];
    }
  }
  __syncthreads();

  // conv1: 7x7, 1->3, fp32, quad-of-4 outputs per unit (196 units/img)
  #pragma unroll 1
  for (int r = 0; r < 2; ++r) {
    int unit0 = u + 128 * r;
    int unit = imin(unit0, 195);
    int y = unit / 7, x0 = (unit % 7) * 4;
    float acc[4][3] = {};
    #pragma unroll
    for (int ky = 0; ky < 7; ++ky) {
      const float* row = SAf + (y + ky) * 36 + x0;
      float win[12];
      #pragma unroll
      for (int v = 0; v < 3; ++v) {
        float4 f = *(const float4*)(row + 4 * v);
        win[4 * v] = f.x; win[4 * v + 1] = f.y; win[4 * v + 2] = f.z; win[4 * v + 3] = f.w;
      }
      #pragma unroll
      for (int co = 0; co < 3; ++co)
        #pragma unroll
        for (int kx = 0; kx < 7; ++kx) {
          float w = WSf[co * 49 + ky * 7 + kx];
          #pragma unroll
          for (int i = 0; i < 4; ++i)
            acc[i][co] = fmaf(win[i + kx], w, acc[i][co]);
        }
    }
    if (unit0 < 196) {
      #pragma unroll
      for (int i = 0; i < 4; ++i) {
        int o = (y + 2) * 36 + (x0 + i + 2);
        SB[o] = pack_relu(acc[i][0], acc[i][1]);
        SB[1152 + o] = pack_relu(acc[i][2], 0.0f);
      }
    }
  }
  __syncthreads();

  // zero a2p; stage w2
  for (int i = u; i < 3364; i += 128) SA[i] = 0;
  for (int i = t; i < 400; i += 256) WS[i] = wp[W2P + i];
  __syncthreads();

  // conv2: 5x5, cin 3(2 pairs), cout 8, quad-of-4 outputs
  #pragma unroll 1
  for (int r = 0; r < 2; ++r) {
    int unit0 = u + 128 * r;
    int unit = imin(unit0, 195);
    int y = unit / 7, x0 = (unit % 7) * 4;
    float acc[4][8] = {};
    #pragma unroll
    for (int cp = 0; cp < 2; ++cp)
      #pragma unroll
      for (int ky = 0; ky < 5; ++ky) {
        const u32* row = SB + cp * 1152 + (y + ky) * 36 + x0;
        uint4 A0 = *(const uint4*)row;
        uint4 A1 = *(const uint4*)(row + 4);
        u32 win[8] = {A0.x, A0.y, A0.z, A0.w, A1.x, A1.y, A1.z, A1.w};
        const u32* ws = WS + (cp * 5 + ky) * 40;
        #pragma unroll
        for (int kx = 0; kx < 5; ++kx)
          #pragma unroll
          for (int co = 0; co < 8; ++co) {
            u32 w = ws[kx * 8 + co];
            #pragma unroll
            for (int i = 0; i < 4; ++i)
              acc[i][co] = dot2(win[i + kx], w, acc[i][co]);
          }
      }
    if (unit0 < 196) {
      #pragma unroll
      for (int i = 0; i < 4; ++i) {
        int o = (y + 1) * 29 + (x0 + i + 1);
        SA[o] = pack_relu(acc[i][0], acc[i][1]);
        SA[841 + o] = pack_relu(acc[i][2], acc[i][3]);
        SA[1682 + o] = pack_relu(acc[i][4], acc[i][5]);
        SA[2523 + o] = pack_relu(acc[i][6], acc[i][7]);
      }
    }
  }
  __syncthreads();

  // zero p1p; stage w3
  for (int i = u; i < 1152; i += 128) SB[i] = 0;
  for (int i = t; i < 384; i += 256) WS[i] = wp[W3P + i];
  __syncthreads();

  // pool1 3x3 s2 p1: a2p(29) -> p1p[4][16][18]
  for (int q = u; q < 784; q += 128) {
    int cp = q / 196, r = q % 196, y = r / 14, x = r % 14;
    const u32* basep = SA + cp * 841 + (2 * y) * 29 + 2 * x;
    u32 m = 0;
    #pragma unroll
    for (int j = 0; j < 3; ++j)
      #pragma unroll
      for (int k = 0; k < 3; ++k) m = max2(m, basep[j * 29 + k]);
    SB[cp * 288 + (y + 1) * 18 + (x + 1)] = m;
  }
  __syncthreads();

  // zero a3p
  for (int i = u; i < 1440; i += 128) SA[i] = 0;
  __syncthreads();

  // conv3: 3x3, cin 8(4 pairs), cout 10, pair-of-2 outputs (98 units/img)
  {
    int unit = imin(u, 97);
    int y = unit / 7, x0 = (unit % 7) * 2;
    float acc[2][10] = {};
    #pragma unroll
    for (int cp = 0; cp < 4; ++cp)
      #pragma unroll
      for (int ky = 0; ky < 3; ++ky) {
        const u32* row = SB + cp * 288 + (y + ky) * 18 + x0;
        uint2 A0 = *(const uint2*)row;
        uint2 A1 = *(const uint2*)(row + 2);
        u32 win[4] = {A0.x, A0.y, A1.x, A1.y};
        const u32* ws = WS + (cp * 3 + ky) * 32;
        #pragma unroll
        for (int kx = 0; kx < 3; ++kx)
          #pragma unroll
          for (int co = 0; co < 10; ++co) {
            u32 w = ws[kx * 10 + co];
            #pragma unroll
            for (int i = 0; i < 2; ++i)
              acc[i][co] = dot2(win[i + kx], w, acc[i][co]);
          }
      }
    if (u < 98) {
      #pragma unroll
      for (int i = 0; i < 2; ++i) {
        int o = (y + 1) * 18 + (x0 + i + 1);
        #pragma unroll
        for (int c = 0; c < 5; ++c) SA[c * 288 + o] = pack_relu(acc[i][2 * c], acc[i][2 * c + 1]);
      }
    }
  }
  __syncthreads();

  // zero a4p; stage w4
  for (int i = u; i < 1800; i += 128) SB[i] = 0;
  for (int i = t; i < 720; i += 256) WS[i] = wp[W4P + i];
  __syncthreads();

  // conv4: 3x3, cin 10(5 pairs), cout 16, pair-of-2 outputs
  {
    int unit = imin(u, 97);
    int y = unit / 7, x0 = (unit % 7) * 2;
    float acc[2][16] = {};
    #pragma unroll
    for (int cp = 0; cp < 5; ++cp)
      #pragma unroll
      for (int ky = 0; ky < 3; ++ky) {
        const u32* row = SA + cp * 288 + (y + ky) * 18 + x0;
        uint2 A0 = *(const uint2*)row;
        uint2 A1 = *(const uint2*)(row + 2);
        u32 win[4] = {A0.x, A0.y, A1.x, A1.y};
        const u32* ws = WS + (cp * 3 + ky) * 48;
        #pragma unroll
        for (int kx = 0; kx < 3; ++kx)
          #pragma unroll
          for (int co = 0; co < 16; ++co) {
            u32 w = ws[kx * 16 + co];
            #pragma unroll
            for (int i = 0; i < 2; ++i)
              acc[i][co] = dot2(win[i + kx], w, acc[i][co]);
          }
      }
    if (u < 98) {
      #pragma unroll
      for (int i = 0; i < 2; ++i) {
        int o = (y + 1) * 15 + (x0 + i + 1);
        #pragma unroll
        for (int c = 0; c < 8; ++c) SB[c * 225 + o] = pack_relu(acc[i][2 * c], acc[i][2 * c + 1]);
      }
    }
  }
  __syncthreads();

  // zero p2p; stage w5
  for (int i = u; i < 648; i += 128) SA[i] = 0;
  for (int i = t; i < 1728; i += 256) WS[i] = wp[W5P + i];
  __syncthreads();

  // pool2 3x3 s2 p1: a4p(15) -> p2p[8][9][9]
  for (int q = u; q < 392; q += 128) {
    int cp = q / 49, r = q % 49, y = r / 7, x = r % 7;
    const u32* basep = SB + cp * 225 + (2 * y) * 15 + 2 * x;
    u32 m = 0;
    #pragma unroll
    for (int j = 0; j < 3; ++j)
      #pragma unroll
      for (int k = 0; k < 3; ++k) m = max2(m, basep[j * 15 + k]);
    SA[cp * 81 + (y + 1) * 9 + (x + 1)] = m;
  }
  __syncthreads();

  // conv5: 3x3, cin 16(8 pairs), cout 24; waves {0,1}:co 0..11, {2,3}:co 12..23
  {
    int w_ = t >> 6, lane = t & 63;
    int cog = w_ >> 1;
    int unit0 = ((w_ & 1) << 6) + lane;  // 0..127
    int unit = imin(unit0, 97);
    int im = unit / 49, pxu = unit % 49;
    int y = pxu / 7, x = pxu % 7;
    u32* SA2 = smem + im * AR;
    u32* SB2 = SA2 + AR_A;
    float acc[12] = {};
    #pragma unroll
    for (int cp = 0; cp < 8; ++cp)
      #pragma unroll
      for (int ky = 0; ky < 3; ++ky) {
        const u32* row = SA2 + cp * 81 + (y + ky) * 9 + x;
        u32 a0 = row[0], a1 = row[1], a2 = row[2];
        const u32* ws = WS + (cp * 3 + ky) * 72 + cog * 12;
        #pragma unroll
        for (int j = 0; j < 12; ++j) acc[j] = dot2(a0, ws[j], acc[j]);
        #pragma unroll
        for (int j = 0; j < 12; ++j) acc[j] = dot2(a1, ws[24 + j], acc[j]);
        #pragma unroll
        for (int j = 0; j < 12; ++j) acc[j] = dot2(a2, ws[48 + j], acc[j]);
      }
    if (unit0 < 98) {
      int o = y * 7 + x;
      #pragma unroll
      for (int c = 0; c < 6; ++c)
        SB2[(6 * cog + c) * 49 + o] = pack_relu(acc[2 * c], acc[2 * c + 1]);
    }
  }
  __syncthreads();

  // stage wd; pool3 3x3 s2 p0: a5p -> p3[12][3][3] at SA[0..107]
  for (int i = t; i < 1080; i += 256) WS[i] = wp[WDP + i];
  for (int q = u; q < 108; q += 128) {
    int cp = q / 9, r = q % 9, y = r / 3, x = r % 3;
    const u32* basep = SB + cp * 49 + (2 * y) * 7 + 2 * x;
    u32 m = 0;
    #pragma unroll
    for (int j = 0; j < 3; ++j)
      #pragma unroll
      for (int k = 0; k < 3; ++k) m = max2(m, basep[j * 7 + k]);
    SA[cp * 9 + r] = m;
  }
  __syncthreads();

  // dense: 2 img x 10 outs x 12 chunks of 9 pairs
  if (t < 240) {
    int im = t / 120, r = t % 120, o = r / 12, c = r % 12;
    const u32* p3 = smem + im * AR;
    const u32* wrow = WS + o * 108 + c * 9;
    float acc = 0.f;
    #pragma unroll
    for (int s = 0; s < 9; ++s) acc = dot2(p3[c * 9 + s], wrow[s], acc);
    ((float*)(smem + im * AR))[128 + o * 12 + c] = acc;
  }
  __syncthreads();
  if (t < 20) {
    int im = t / 10, o = t % 10;
    const float* par = (const float*)(smem + im * AR) + 128 + o * 12;
    float s = 0.f;
    #pragma unroll
    for (int c = 0; c < 12; ++c) s += par[c];
    out[((long long)blockIdx.x * 2 + im) * 10 + o] = s;
  }
}

extern "C" void kernel_launch(void* const* d_in, const int* in_sizes, int n_in,
                              void* d_out, int out_size, void* d_ws, size_t ws_size,
                              hipStream_t stream) {
  const float* in = (const float*)d_in[0];
  const float* w1 = (const float*)d_in[1];
  const float* w2 = (const float*)d_in[2];
  const float* w3 = (const float*)d_in[3];
  const float* w4 = (const float*)d_in[4];
  const float* w5 = (const float*)d_in[5];
  const float* wd = (const float*)d_in[6];
  u32* wp = (u32*)d_ws;
  float* out = (float*)d_out;
  int B = in_sizes[0] / 784;

  prep_weights<<<(WTOT + 255) / 256, 256, 0, stream>>>(w2, w3, w4, w5, wd, wp);
  mnist_fused<<<B / 2, 256, 0, stream>>>(in, w1, wp, out);
}

// Round 7
// 619.065 us; speedup vs baseline: 1.2680x; 1.2680x over previous
//
#include <hip/hip_runtime.h>
#include <hip/hip_bf16.h>

typedef _Float16 half2v __attribute__((ext_vector_type(2)));
typedef unsigned int u32;

// single-instruction packed f16 dot with f32 accumulate
__device__ __forceinline__ float dot2(u32 a, u32 b, float c) {
  float d;
  asm("v_dot2_f32_f16 %0, %1, %2, %3" : "=v"(d) : "v"(a), "v"(b), "v"(c));
  return d;
}

// pack two f32 -> f16x2, as u32
__device__ __forceinline__ u32 pkrtz(float a, float b) {
  return __builtin_bit_cast(u32, __builtin_amdgcn_cvt_pkrtz(a, b));
}

__device__ __forceinline__ u32 pack_relu(float a, float b) {
  return pkrtz(fmaxf(a, 0.0f), fmaxf(b, 0.0f));
}

__device__ __forceinline__ u32 max2(u32 a, u32 b) {
  half2v x = __builtin_bit_cast(half2v, a);
  half2v y = __builtin_bit_cast(half2v, b);
  x.x = (y.x > x.x) ? y.x : x.x;
  x.y = (y.y > x.y) ? y.y : x.y;
  return __builtin_bit_cast(u32, x);
}

__device__ __forceinline__ int imin(int a, int b) { return a < b ? a : b; }

// ---- packed weight layout in d_ws (u32 = one half2 pair) ---------------
#define W2P 0       // [2][5][5kx][8co]          = 400
#define W3P 400     // [4][3][32: kx*10+co pad]  = 384
#define W4P 784     // [5][3][3kx][16co]         = 720
#define W5P 1504    // [8][3][3kx][24co]         = 1728
#define WDP 3232    // [10][108]                 = 1080
#define WTOT 4312

__global__ void __launch_bounds__(256) prep_weights(
    const float* __restrict__ w2, const float* __restrict__ w3,
    const float* __restrict__ w4, const float* __restrict__ w5,
    const float* __restrict__ wd, u32* __restrict__ wp) {
  int i = threadIdx.x + blockIdx.x * 256;
  if (i < 400) {  // w2: src [8][3][5][5]
    int co = i & 7, r = i >> 3;
    int kx = r % 5, ky = (r / 5) % 5, cp = r / 25;
    int s = ky * 5 + kx;
    float lo = w2[co * 75 + (2 * cp) * 25 + s];
    float hi = (2 * cp + 1 < 3) ? w2[co * 75 + (2 * cp + 1) * 25 + s] : 0.0f;
    wp[W2P + i] = pkrtz(lo, hi);
  } else if (i < 784) {  // w3: src [10][8][3][3]
    int j = i - 400;
    int b = j >> 5, e = j & 31;
    int cp = b / 3, ky = b % 3;
    u32 v = 0;
    if (e < 30) {
      int kx = e / 10, co = e % 10, s = ky * 3 + kx;
      v = pkrtz(w3[co * 72 + (2 * cp) * 9 + s], w3[co * 72 + (2 * cp + 1) * 9 + s]);
    }
    wp[W3P + j] = v;
  } else if (i < 1504) {  // w4: src [16][10][3][3]
    int j = i - 784;
    int co = j & 15, r = j >> 4;
    int kx = r % 3, ky = (r / 3) % 3, cp = r / 9;
    int s = ky * 3 + kx;
    wp[W4P + j] = pkrtz(w4[co * 90 + (2 * cp) * 9 + s], w4[co * 90 + (2 * cp + 1) * 9 + s]);
  } else if (i < 3232) {  // w5: src [24][16][3][3]
    int j = i - 1504;
    int co = j % 24, r = j / 24;
    int kx = r % 3, ky = (r / 3) % 3, cp = r / 9;
    int s = ky * 3 + kx;
    wp[W5P + j] = pkrtz(w5[co * 144 + (2 * cp) * 9 + s], w5[co * 144 + (2 * cp + 1) * 9 + s]);
  } else if (i < WTOT) {  // wd: src [10][216], k = ci*9 + s
    int j = i - 3232;
    int o = j / 108, r = j % 108, cp = r / 9, s = r % 9;
    wp[WDP + j] = pkrtz(wd[o * 216 + (2 * cp) * 9 + s], wd[o * 216 + (2 * cp + 1) * 9 + s]);
  }
}

// ---- fused network: 2 images per 256-thread block ----------------------
// Arena A (per img): in_p f32[34][36](1224) -> a2p[4][29][29](3364)
//   -> a3p[5][16][16](1280) -> p2p[8][9][9](648) -> p3(108)+dense partials
// Arena B (per img): a1p[2][32][36](2304) -> p1p[4][16][16](1024)
//   -> a4p[8][15][15](1800) -> a5p[12][7][7](588)
// in_p/a1p stride 36: quad bases 16B-aligned, rows rotate banks (36%32=4).
#define AR_A 3376
#define AR_B 2304
#define AR (AR_A + AR_B)
#define WSOFF (2 * AR)
#define SMEMN (2 * AR + 1728)  // 13088 u32 = 52352 B -> 3 blocks/CU

__global__ void __launch_bounds__(256) mnist_fused(
    const float* __restrict__ in, const float* __restrict__ w1,
    const u32* __restrict__ wp, float* __restrict__ out) {
  __shared__ __align__(16) u32 smem[SMEMN];
  const int t = threadIdx.x;
  const int u = t & 127;
  const int img = t >> 7;
  const long long b = (long long)blockIdx.x * 2 + img;
  u32* SA = smem + img * AR;
  u32* SB = SA + AR_A;
  float* SAf = (float*)SA;
  u32* WS = smem + WSOFF;
  float* WSf = (float*)WS;

  // phase 0: zero in_p + a1p, stage w1 (147 f32)
  for (int i = u; i < 1224; i += 128) SA[i] = 0;
  for (int i = u; i < 2304; i += 128) SB[i] = 0;
  for (int i = t; i < 147; i += 256) WSf[i] = w1[i];
  __syncthreads();

  // stage input (fp32, halo 3, stride 36)
  {
    const float* inb = in + b * 784;
    for (int p = u; p < 784; p += 128) {
      int y = p / 28, x = p % 28;
      SAf[(y + 3) * 36 + (x + 3)] = inb[p];
    }
  }
  __syncthreads();

  // conv1: 7x7, 1->3, fp32, quad-of-4 outputs per unit (196 units/img)
  #pragma unroll 1
  for (int r = 0; r < 2; ++r) {
    int unit0 = u + 128 * r;
    int unit = imin(unit0, 195);
    int y = unit / 7, x0 = (unit % 7) * 4;
    float acc[4][3] = {};
    #pragma unroll 1
    for (int ky = 0; ky < 7; ++ky) {
      float wk[21];
      #pragma unroll
      for (int co = 0; co < 3; ++co)
        #pragma unroll
        for (int kx = 0; kx < 7; ++kx) wk[co * 7 + kx] = WSf[co * 49 + ky * 7 + kx];
      const float* row = SAf + (y + ky) * 36 + x0;
      float win[12];
      #pragma unroll
      for (int v = 0; v < 3; ++v) {
        float4 f = *(const float4*)(row + 4 * v);
        win[4 * v] = f.x; win[4 * v + 1] = f.y; win[4 * v + 2] = f.z; win[4 * v + 3] = f.w;
      }
      #pragma unroll
      for (int co = 0; co < 3; ++co)
        #pragma unroll
        for (int kx = 0; kx < 7; ++kx) {
          float w = wk[co * 7 + kx];
          #pragma unroll
          for (int i = 0; i < 4; ++i)
            acc[i][co] = fmaf(win[i + kx], w, acc[i][co]);
        }
    }
    if (unit0 < 196) {
      #pragma unroll
      for (int i = 0; i < 4; ++i) {
        int o = (y + 2) * 36 + (x0 + i + 2);
        SB[o] = pack_relu(acc[i][0], acc[i][1]);
        SB[1152 + o] = pack_relu(acc[i][2], 0.0f);
      }
    }
  }
  __syncthreads();

  // zero a2p; stage w2
  for (int i = u; i < 3364; i += 128) SA[i] = 0;
  for (int i = t; i < 400; i += 256) WS[i] = wp[W2P + i];
  __syncthreads();

  // conv2: 5x5, cin 3(2 pairs), cout 8, quad-of-4 outputs
  #pragma unroll 1
  for (int r = 0; r < 2; ++r) {
    int unit0 = u + 128 * r;
    int unit = imin(unit0, 195);
    int y = unit / 7, x0 = (unit % 7) * 4;
    float acc[4][8] = {};
    #pragma unroll 1
    for (int cp = 0; cp < 2; ++cp)
      #pragma unroll 1
      for (int ky = 0; ky < 5; ++ky) {
        u32 w[40];
        int blk = (cp * 5 + ky) * 40;
        #pragma unroll
        for (int q = 0; q < 40; ++q) w[q] = WS[blk + q];
        const u32* row = SB + cp * 1152 + (y + ky) * 36 + x0;
        uint4 A0 = *(const uint4*)row;
        uint4 A1 = *(const uint4*)(row + 4);
        u32 win[8] = {A0.x, A0.y, A0.z, A0.w, A1.x, A1.y, A1.z, A1.w};
        #pragma unroll
        for (int kx = 0; kx < 5; ++kx)
          #pragma unroll
          for (int co = 0; co < 8; ++co) {
            u32 wv = w[kx * 8 + co];
            #pragma unroll
            for (int i = 0; i < 4; ++i)
              acc[i][co] = dot2(win[i + kx], wv, acc[i][co]);
          }
      }
    if (unit0 < 196) {
      #pragma unroll
      for (int i = 0; i < 4; ++i) {
        int o = (y + 1) * 29 + (x0 + i + 1);
        SA[o] = pack_relu(acc[i][0], acc[i][1]);
        SA[841 + o] = pack_relu(acc[i][2], acc[i][3]);
        SA[1682 + o] = pack_relu(acc[i][4], acc[i][5]);
        SA[2523 + o] = pack_relu(acc[i][6], acc[i][7]);
      }
    }
  }
  __syncthreads();

  // zero p1p; stage w3
  for (int i = u; i < 1024; i += 128) SB[i] = 0;
  for (int i = t; i < 384; i += 256) WS[i] = wp[W3P + i];
  __syncthreads();

  // pool1 3x3 s2 p1: a2p(29) -> p1p[4][16][16]
  for (int q = u; q < 784; q += 128) {
    int cp = q / 196, r = q % 196, y = r / 14, x = r % 14;
    const u32* basep = SA + cp * 841 + (2 * y) * 29 + 2 * x;
    u32 m = 0;
    #pragma unroll
    for (int j = 0; j < 3; ++j)
      #pragma unroll
      for (int k = 0; k < 3; ++k) m = max2(m, basep[j * 29 + k]);
    SB[cp * 256 + (y + 1) * 16 + (x + 1)] = m;
  }
  __syncthreads();

  // zero a3p
  for (int i = u; i < 1280; i += 128) SA[i] = 0;
  __syncthreads();

  // conv3: 3x3, cin 8(4 pairs), cout 10 -> a3p[5][16][16]
  {
    float acc[2][10] = {};
    int yy[2], xx[2];
    #pragma unroll
    for (int i = 0; i < 2; ++i) { int p = u + 128 * i; yy[i] = p / 14; xx[i] = p % 14; }
    #pragma unroll 1
    for (int cp = 0; cp < 4; ++cp)
      #pragma unroll 1
      for (int ky = 0; ky < 3; ++ky) {
        u32 w[32];
        int blk = (cp * 3 + ky) * 32;
        #pragma unroll
        for (int q = 0; q < 32; ++q) w[q] = WS[blk + q];
        #pragma unroll
        for (int i = 0; i < 2; ++i) {
          int p = u + 128 * i;
          if (p < 196) {
            const u32* row = SB + cp * 256 + (yy[i] + ky) * 16 + xx[i];
            u32 a[3];
            #pragma unroll
            for (int kx = 0; kx < 3; ++kx) a[kx] = row[kx];
            #pragma unroll
            for (int kx = 0; kx < 3; ++kx)
              #pragma unroll
              for (int co = 0; co < 10; ++co)
                acc[i][co] = dot2(a[kx], w[kx * 10 + co], acc[i][co]);
          }
        }
      }
    #pragma unroll
    for (int i = 0; i < 2; ++i) {
      int p = u + 128 * i;
      if (p < 196) {
        int o = (yy[i] + 1) * 16 + xx[i] + 1;
        #pragma unroll
        for (int c = 0; c < 5; ++c) SA[c * 256 + o] = pack_relu(acc[i][2 * c], acc[i][2 * c + 1]);
      }
    }
  }
  __syncthreads();

  // zero a4p; stage w4
  for (int i = u; i < 1800; i += 128) SB[i] = 0;
  for (int i = t; i < 720; i += 256) WS[i] = wp[W4P + i];
  __syncthreads();

  // conv4: 3x3, cin 10(5 pairs), cout 16 -> a4p[8][15][15]
  {
    float acc[2][16] = {};
    int yy[2], xx[2];
    #pragma unroll
    for (int i = 0; i < 2; ++i) { int p = u + 128 * i; yy[i] = p / 14; xx[i] = p % 14; }
    #pragma unroll 1
    for (int cp = 0; cp < 5; ++cp)
      #pragma unroll 1
      for (int ky = 0; ky < 3; ++ky) {
        u32 w[48];
        int blk = (cp * 3 + ky) * 48;
        #pragma unroll
        for (int q = 0; q < 48; ++q) w[q] = WS[blk + q];
        #pragma unroll
        for (int i = 0; i < 2; ++i) {
          int p = u + 128 * i;
          if (p < 196) {
            const u32* row = SA + cp * 256 + (yy[i] + ky) * 16 + xx[i];
            u32 a[3];
            #pragma unroll
            for (int kx = 0; kx < 3; ++kx) a[kx] = row[kx];
            #pragma unroll
            for (int kx = 0; kx < 3; ++kx)
              #pragma unroll
              for (int co = 0; co < 16; ++co)
                acc[i][co] = dot2(a[kx], w[kx * 16 + co], acc[i][co]);
          }
        }
      }
    #pragma unroll
    for (int i = 0; i < 2; ++i) {
      int p = u + 128 * i;
      if (p < 196) {
        int o = (yy[i] + 1) * 15 + xx[i] + 1;
        #pragma unroll
        for (int c = 0; c < 8; ++c) SB[c * 225 + o] = pack_relu(acc[i][2 * c], acc[i][2 * c + 1]);
      }
    }
  }
  __syncthreads();

  // zero p2p; stage w5
  for (int i = u; i < 648; i += 128) SA[i] = 0;
  for (int i = t; i < 1728; i += 256) WS[i] = wp[W5P + i];
  __syncthreads();

  // pool2 3x3 s2 p1: a4p(15) -> p2p[8][9][9]
  for (int q = u; q < 392; q += 128) {
    int cp = q / 49, r = q % 49, y = r / 7, x = r % 7;
    const u32* basep = SB + cp * 225 + (2 * y) * 15 + 2 * x;
    u32 m = 0;
    #pragma unroll
    for (int j = 0; j < 3; ++j)
      #pragma unroll
      for (int k = 0; k < 3; ++k) m = max2(m, basep[j * 15 + k]);
    SA[cp * 81 + (y + 1) * 9 + (x + 1)] = m;
  }
  __syncthreads();

  // conv5: 3x3, cin 16(8 pairs), cout 24; waves {0,1}:co 0..11, {2,3}:co 12..23
  {
    int w_ = t >> 6, lane = t & 63;
    int cog = w_ >> 1;
    int unit = ((w_ & 1) << 6) + lane;  // 0..127
    int valid = unit < 98;
    int im = valid ? unit / 49 : 0;
    int pxu = unit % 49;
    int y = pxu / 7, x = pxu % 7;
    u32* SA2 = smem + im * AR;
    u32* SB2 = SA2 + AR_A;
    float acc[12] = {};
    #pragma unroll 1
    for (int cp = 0; cp < 8; ++cp)
      #pragma unroll 1
      for (int ky = 0; ky < 3; ++ky) {
        u32 wv[36];
        int base = (cp * 3 + ky) * 72 + cog * 12;
        #pragma unroll
        for (int kx = 0; kx < 3; ++kx)
          #pragma unroll
          for (int j = 0; j < 12; ++j) wv[kx * 12 + j] = WS[base + kx * 24 + j];
        if (valid) {
          const u32* row = SA2 + cp * 81 + (y + ky) * 9 + x;
          u32 a[3];
          #pragma unroll
          for (int kx = 0; kx < 3; ++kx) a[kx] = row[kx];
          #pragma unroll
          for (int kx = 0; kx < 3; ++kx)
            #pragma unroll
            for (int j = 0; j < 12; ++j)
              acc[j] = dot2(a[kx], wv[kx * 12 + j], acc[j]);
        }
      }
    if (valid) {
      int o = y * 7 + x;
      #pragma unroll
      for (int c = 0; c < 6; ++c)
        SB2[(6 * cog + c) * 49 + o] = pack_relu(acc[2 * c], acc[2 * c + 1]);
    }
  }
  __syncthreads();

  // stage wd; pool3 3x3 s2 p0: a5p -> p3[12][3][3] at SA[0..107]
  for (int i = t; i < 1080; i += 256) WS[i] = wp[WDP + i];
  for (int q = u; q < 108; q += 128) {
    int cp = q / 9, r = q % 9, y = r / 3, x = r % 3;
    const u32* basep = SB + cp * 49 + (2 * y) * 7 + 2 * x;
    u32 m = 0;
    #pragma unroll
    for (int j = 0; j < 3; ++j)
      #pragma unroll
      for (int k = 0; k < 3; ++k) m = max2(m, basep[j * 7 + k]);
    SA[cp * 9 + r] = m;
  }
  __syncthreads();

  // dense: 2 img x 10 outs x 12 chunks of 9 pairs
  if (t < 240) {
    int im = t / 120, r = t % 120, o = r / 12, c = r % 12;
    const u32* p3 = smem + im * AR;
    const u32* wrow = WS + o * 108 + c * 9;
    float acc = 0.f;
    #pragma unroll
    for (int s = 0; s < 9; ++s) acc = dot2(p3[c * 9 + s], wrow[s], acc);
    ((float*)(smem + im * AR))[128 + o * 12 + c] = acc;
  }
  __syncthreads();
  if (t < 20) {
    int im = t / 10, o = t % 10;
    const float* par = (const float*)(smem + im * AR) + 128 + o * 12;
    float s = 0.f;
    #pragma unroll
    for (int c = 0; c < 12; ++c) s += par[c];
    out[((long long)blockIdx.x * 2 + im) * 10 + o] = s;
  }
}

extern "C" void kernel_launch(void* const* d_in, const int* in_sizes, int n_in,
                              void* d_out, int out_size, void* d_ws, size_t ws_size,
                              hipStream_t stream) {
  const float* in = (const float*)d_in[0];
  const float* w1 = (const float*)d_in[1];
  const float* w2 = (const float*)d_in[2];
  const float* w3 = (const float*)d_in[3];
  const float* w4 = (const float*)d_in[4];
  const float* w5 = (const float*)d_in[5];
  const float* wd = (const float*)d_in[6];
  u32* wp = (u32*)d_ws;
  float* out = (float*)d_out;
  int B = in_sizes[0] / 784;

  prep_weights<<<(WTOT + 255) / 256, 256, 0, stream>>>(w2, w3, w4, w5, wd, wp);
  mnist_fused<<<B / 2, 256, 0, stream>>>(in, w1, wp, out);
}

// Round 8
// 335.916 us; speedup vs baseline: 2.3367x; 1.8429x over previous
//
#include <hip/hip_runtime.h>
#include <hip/hip_bf16.h>

typedef _Float16 half2v __attribute__((ext_vector_type(2)));
typedef _Float16 f16x8 __attribute__((ext_vector_type(8)));
typedef float f32x4 __attribute__((ext_vector_type(4)));
typedef unsigned int u32;

__device__ __forceinline__ float dot2(u32 a, u32 b, float c) {
  float d;
  asm("v_dot2_f32_f16 %0, %1, %2, %3" : "=v"(d) : "v"(a), "v"(b), "v"(c));
  return d;
}
__device__ __forceinline__ u32 pkrtz(float a, float b) {
  return __builtin_bit_cast(u32, __builtin_amdgcn_cvt_pkrtz(a, b));
}
__device__ __forceinline__ u32 pack_relu(float a, float b) {
  return pkrtz(fmaxf(a, 0.0f), fmaxf(b, 0.0f));
}
__device__ __forceinline__ u32 max2(u32 a, u32 b) {
  half2v x = __builtin_bit_cast(half2v, a);
  half2v y = __builtin_bit_cast(half2v, b);
  x.x = (y.x > x.x) ? y.x : x.x;
  x.y = (y.y > x.y) ? y.y : x.y;
  return __builtin_bit_cast(u32, x);
}
__device__ __forceinline__ int imin(int a, int b) { return a < b ? a : b; }

// ---- weight A-fragment layout in d_ws (u32 = f16 pair) -----------------
// A-frag for mfma_f32_16x16x32_f16: lane l holds A[row=l&15][k=8*(l>>4)+j],
// j=0..7, as 4 u32. Stored per layer per k-group g: [g][lane][4].
#define W2F 0      // conv2: 4 g  (k = tap*4+ci, taps 5x5 row-major, ci pad4)
#define W3F 1024   // conv3: 3 g  (k = tap*8+ci, taps 3x3)
#define W4F 1792   // conv4: 5 g  (k = tap*16+ci, ci pad16)
#define W5F 3072   // conv5: 2 cot x 5 g
#define WDF 5632   // dense: [10][12cp][9px] pairs (cp = ci-pair)
#define WTOT 6712

__global__ void __launch_bounds__(256) prep_weights(
    const float* __restrict__ w2, const float* __restrict__ w3,
    const float* __restrict__ w4, const float* __restrict__ w5,
    const float* __restrict__ wd, u32* __restrict__ wp) {
  int i = threadIdx.x + blockIdx.x * 256;
  if (i < 1024) {  // conv2 A-frags: w2 [8co][3ci][5][5]
    int g = i >> 8, rem = i & 255, l = rem >> 2, r = rem & 3;
    int s = l >> 4, co = l & 15;
    float v[2];
    #pragma unroll
    for (int e = 0; e < 2; ++e) {
      int k = g * 32 + 8 * s + 2 * r + e;
      int t = k >> 2, ci = k & 3;
      v[e] = (co < 8 && ci < 3 && t < 25) ? w2[co * 75 + ci * 25 + t] : 0.0f;
    }
    wp[W2F + i] = pkrtz(v[0], v[1]);
  } else if (i < 1792) {  // conv3: w3 [10co][8ci][3][3]
    int q = i - W3F;
    int g = q >> 8, rem = q & 255, l = rem >> 2, r = rem & 3;
    int s = l >> 4, co = l & 15;
    float v[2];
    #pragma unroll
    for (int e = 0; e < 2; ++e) {
      int k = g * 32 + 8 * s + 2 * r + e;
      int t = k >> 3, ci = k & 7;
      v[e] = (co < 10 && t < 9) ? w3[co * 72 + ci * 9 + t] : 0.0f;
    }
    wp[W3F + q] = pkrtz(v[0], v[1]);
  } else if (i < 3072) {  // conv4: w4 [16co][10ci][3][3]
    int q = i - W4F;
    int g = q >> 8, rem = q & 255, l = rem >> 2, r = rem & 3;
    int s = l >> 4, co = l & 15;
    float v[2];
    #pragma unroll
    for (int e = 0; e < 2; ++e) {
      int k = g * 32 + 8 * s + 2 * r + e;
      int t = k >> 4, ci = k & 15;
      v[e] = (ci < 10 && t < 9) ? w4[co * 90 + ci * 9 + t] : 0.0f;
    }
    wp[W4F + q] = pkrtz(v[0], v[1]);
  } else if (i < 5632) {  // conv5: w5 [24co][16ci][3][3], 2 co-tiles
    int q = i - W5F;
    int cot = q / 1280, q2 = q % 1280;
    int g = q2 >> 8, rem = q2 & 255, l = rem >> 2, r = rem & 3;
    int s = l >> 4, co = cot * 16 + (l & 15);
    float v[2];
    #pragma unroll
    for (int e = 0; e < 2; ++e) {
      int k = g * 32 + 8 * s + 2 * r + e;
      int t = k >> 4, ci = k & 15;
      v[e] = (co < 24 && t < 9) ? w5[co * 144 + ci * 9 + t] : 0.0f;
    }
    wp[W5F + q] = pkrtz(v[0], v[1]);
  } else if (i < WTOT) {  // dense: wd [10][216], k = ci*9 + px
    int j = i - WDF;
    int o = j / 108, r = j % 108, cp = r / 9, s = r % 9;
    wp[WDF + j] = pkrtz(wd[o * 216 + (2 * cp) * 9 + s],
                        wd[o * 216 + (2 * cp + 1) * 9 + s]);
  }
}

// ---- fused network: 2 images per 256-thread block ----------------------
// Channels-last f16 activations (u32 = ci-pair). Per image:
//  Arena A (3600): IN f32[34][36](1224) -> a2[30][30][8ci](3600)
//    -> a3[16][16][16ci](2048) -> p2[9][9][16ci](648) -> p3(108)+partials
//  Arena B (2048): a1[32][32][4ci](2048) -> p1[16][16][8ci](1024)
//    -> a4[16][16][16ci](2048) -> a5[7][7][24ci](588)
#define AR_A 3600
#define AR_B 2048
#define AR (AR_A + AR_B)
#define WSOFF (2 * AR)
#define SMEMN (2 * AR + 1080)  // 12376 u32 = 49504 B -> 3 blocks/CU

__device__ __forceinline__ f32x4 mfma16(uint4 a, uint4 b, f32x4 c) {
  return __builtin_amdgcn_mfma_f32_16x16x32_f16(
      __builtin_bit_cast(f16x8, a), __builtin_bit_cast(f16x8, b), c, 0, 0, 0);
}

__global__ void __launch_bounds__(256) mnist_fused(
    const float* __restrict__ in, const float* __restrict__ w1,
    const u32* __restrict__ wp, float* __restrict__ out) {
  __shared__ __align__(16) u32 smem[SMEMN];
  const int t = threadIdx.x;
  const int u = t & 127;
  const int img = t >> 7;
  const int lane = t & 63;
  const int wid = t >> 6;
  const long long b = (long long)blockIdx.x * 2 + img;
  u32* SA = smem + img * AR;
  u32* SB = SA + AR_A;
  float* SAf = (float*)SA;
  u32* WS = smem + WSOFF;
  float* WSf = (float*)WS;

  // per-lane mfma identities (col n -> (pixel-group, image))
  const int s_ = lane >> 4, n_ = lane & 15;
  const int nimg = n_ & 1, pxg = n_ >> 1;
  u32* NA = smem + nimg * AR;       // arena A of this lane's image
  u32* NB = NA + AR_A;              // arena B

  // P0: zero IN + a1, stage w1 (147 f32)
  for (int i = u; i < 1224; i += 128) SA[i] = 0;
  for (int i = u; i < 2048; i += 128) SB[i] = 0;
  for (int i = t; i < 147; i += 256) WSf[i] = w1[i];
  __syncthreads();

  // P1: stage input (fp32, halo 3, stride 36)
  {
    const float* inb = in + b * 784;
    for (int p = u; p < 784; p += 128) {
      int y = p / 28, x = p % 28;
      SAf[(y + 3) * 36 + (x + 3)] = inb[p];
    }
  }
  __syncthreads();

  // P2: conv1 7x7 1->3 fp32 quad -> a1 [32][32][2pairs] (ci: c0c1, c2pad)
  #pragma unroll 1
  for (int r = 0; r < 2; ++r) {
    int unit0 = u + 128 * r;
    int unit = imin(unit0, 195);
    int y = unit / 7, x0 = (unit % 7) * 4;
    float acc[4][3] = {};
    #pragma unroll 1
    for (int ky = 0; ky < 7; ++ky) {
      float wk[21];
      #pragma unroll
      for (int co = 0; co < 3; ++co)
        #pragma unroll
        for (int kx = 0; kx < 7; ++kx) wk[co * 7 + kx] = WSf[co * 49 + ky * 7 + kx];
      const float* row = SAf + (y + ky) * 36 + x0;
      float win[12];
      #pragma unroll
      for (int v = 0; v < 3; ++v) {
        float4 f = *(const float4*)(row + 4 * v);
        win[4 * v] = f.x; win[4 * v + 1] = f.y; win[4 * v + 2] = f.z; win[4 * v + 3] = f.w;
      }
      #pragma unroll
      for (int co = 0; co < 3; ++co)
        #pragma unroll
        for (int kx = 0; kx < 7; ++kx) {
          float w = wk[co * 7 + kx];
          #pragma unroll
          for (int i = 0; i < 4; ++i)
            acc[i][co] = fmaf(win[i + kx], w, acc[i][co]);
        }
    }
    if (unit0 < 196) {
      #pragma unroll
      for (int i = 0; i < 4; ++i) {
        int o = ((y + 2) * 32 + (x0 + i + 2)) * 2;
        SB[o] = pack_relu(acc[i][0], acc[i][1]);
        SB[o + 1] = pack_relu(acc[i][2], 0.0f);
      }
    }
  }
  __syncthreads();

  // P3: zero a2
  for (int i = u; i < 3600; i += 128) SA[i] = 0;
  __syncthreads();

  // P4: conv2 MFMA. M=co8, N=(8px,2img), K=25taps*4ci -> 4 k-groups
  {
    uint4 af[4];
    const uint4* wq = (const uint4*)(wp + W2F);
    #pragma unroll
    for (int g = 0; g < 4; ++g) af[g] = wq[g * 64 + lane];
    int ro0[4], ro1[4];
    #pragma unroll
    for (int g = 0; g < 4; ++g) {
      int t0 = imin(g * 8 + 2 * s_, 24), t1 = imin(g * 8 + 2 * s_ + 1, 24);
      ro0[g] = ((t0 / 5) * 32 + t0 % 5) * 2;
      ro1[g] = ((t1 / 5) * 32 + t1 % 5) * 2;
    }
    #pragma unroll 1
    for (int j = wid; j < 98; j += 4) {
      int px = j * 8 + pxg;
      int y = px / 28, x = px % 28;
      int ab = (y * 32 + x) * 2;
      f32x4 acc = {0.f, 0.f, 0.f, 0.f};
      #pragma unroll
      for (int g = 0; g < 4; ++g) {
        uint2 lo = *(const uint2*)(NB + ab + ro0[g]);
        uint2 hi = *(const uint2*)(NB + ab + ro1[g]);
        uint4 bv = {lo.x, lo.y, hi.x, hi.y};
        acc = mfma16(af[g], bv, acc);
      }
      if (s_ < 2) {  // rows co = 4s..4s+3 valid (co<8)
        int ob = ((y + 1) * 30 + (x + 1)) * 4;
        NA[ob + 2 * s_] = pack_relu(acc[0], acc[1]);
        NA[ob + 2 * s_ + 1] = pack_relu(acc[2], acc[3]);
      }
    }
  }
  __syncthreads();

  // P5: zero p1
  for (int i = u; i < 1024; i += 128) SB[i] = 0;
  __syncthreads();

  // P6: pool1 3x3 s2 p1: a2[30][30][4] -> p1[16][16][4]
  for (int q = u; q < 784; q += 128) {
    int cp = q & 3, pxq = q >> 2;
    int y = pxq / 14, x = pxq % 14;
    const u32* basep = SA + ((2 * y) * 30 + 2 * x) * 4 + cp;
    u32 m = 0;
    #pragma unroll
    for (int jj = 0; jj < 3; ++jj)
      #pragma unroll
      for (int kk = 0; kk < 3; ++kk) m = max2(m, basep[(jj * 30 + kk) * 4]);
    SB[((y + 1) * 16 + (x + 1)) * 4 + cp] = m;
  }
  __syncthreads();

  // P7: zero a3
  for (int i = u; i < 2048; i += 128) SA[i] = 0;
  __syncthreads();

  // P8: conv3 MFMA. M=co10, K=9taps*8ci -> 3 g, B-read = 1 b128
  {
    uint4 af[3];
    const uint4* wq = (const uint4*)(wp + W3F);
    #pragma unroll
    for (int g = 0; g < 3; ++g) af[g] = wq[g * 64 + lane];
    int roff[3];
    #pragma unroll
    for (int g = 0; g < 3; ++g) {
      int tt = imin(g * 4 + s_, 8);
      roff[g] = ((tt / 3) * 16 + tt % 3) * 4;
    }
    #pragma unroll 1
    for (int j = wid; j < 25; j += 4) {
      int px0 = j * 8 + pxg;
      int px = imin(px0, 195);
      int y = px / 14, x = px % 14;
      int ab = (y * 16 + x) * 4;
      f32x4 acc = {0.f, 0.f, 0.f, 0.f};
      #pragma unroll
      for (int g = 0; g < 3; ++g) {
        uint4 bv = *(const uint4*)(NB + ab + roff[g]);
        acc = mfma16(af[g], bv, acc);
      }
      if (px0 < 196) {
        int ob = ((y + 1) * 16 + (x + 1)) * 8;
        int cp0 = 2 * s_, cp1 = 2 * s_ + 1;
        u32 p0 = pack_relu(acc[0], acc[1]);
        u32 p1v = pack_relu(acc[2], acc[3]);
        if (cp0 < 5) NA[ob + cp0] = p0;
        if (cp1 < 5) NA[ob + cp1] = p1v;
      }
    }
  }
  __syncthreads();

  // P9: zero a4
  for (int i = u; i < 2048; i += 128) SB[i] = 0;
  __syncthreads();

  // P10: conv4 MFMA. M=co16, K=9taps*16ci -> 5 g
  {
    uint4 af[5];
    const uint4* wq = (const uint4*)(wp + W4F);
    #pragma unroll
    for (int g = 0; g < 5; ++g) af[g] = wq[g * 64 + lane];
    int roff[5];
    #pragma unroll
    for (int g = 0; g < 5; ++g) {
      int tt = imin(g * 2 + (s_ >> 1), 8);
      roff[g] = ((tt / 3) * 16 + tt % 3) * 8 + (s_ & 1) * 4;
    }
    #pragma unroll 1
    for (int j = wid; j < 25; j += 4) {
      int px0 = j * 8 + pxg;
      int px = imin(px0, 195);
      int y = px / 14, x = px % 14;
      int ab = (y * 16 + x) * 8;
      f32x4 acc = {0.f, 0.f, 0.f, 0.f};
      #pragma unroll
      for (int g = 0; g < 5; ++g) {
        uint4 bv = *(const uint4*)(NA + ab + roff[g]);
        acc = mfma16(af[g], bv, acc);
      }
      if (px0 < 196) {
        int ob = ((y + 1) * 16 + (x + 1)) * 8;
        NB[ob + 2 * s_] = pack_relu(acc[0], acc[1]);
        NB[ob + 2 * s_ + 1] = pack_relu(acc[2], acc[3]);
      }
    }
  }
  __syncthreads();

  // P11: zero p2
  for (int i = u; i < 648; i += 128) SA[i] = 0;
  __syncthreads();

  // P12: pool2 3x3 s2 p1: a4[16][16][8] -> p2[9][9][8]
  for (int q = u; q < 392; q += 128) {
    int cp = q & 7, pxq = q >> 3;
    int y = pxq / 7, x = pxq % 7;
    const u32* basep = SB + ((2 * y) * 16 + 2 * x) * 8 + cp;
    u32 m = 0;
    #pragma unroll
    for (int jj = 0; jj < 3; ++jj)
      #pragma unroll
      for (int kk = 0; kk < 3; ++kk) m = max2(m, basep[(jj * 16 + kk) * 8]);
    SA[((y + 1) * 9 + (x + 1)) * 8 + cp] = m;
  }
  __syncthreads();

  // P13: conv5 MFMA. M=co (2 tiles of 16), K=9taps*16ci -> 5 g
  {
    int roff[5];
    #pragma unroll
    for (int g = 0; g < 5; ++g) {
      int tt = imin(g * 2 + (s_ >> 1), 8);
      roff[g] = ((tt / 3) * 9 + tt % 3) * 8 + (s_ & 1) * 4;
    }
    #pragma unroll 1
    for (int j = wid; j < 14; j += 4) {
      int cot = j / 7, pj = j - cot * 7;
      uint4 af[5];
      const uint4* wq = (const uint4*)(wp + W5F + cot * 1280);
      #pragma unroll
      for (int g = 0; g < 5; ++g) af[g] = wq[g * 64 + lane];
      int px0 = pj * 8 + pxg;
      int px = imin(px0, 48);
      int y = px / 7, x = px - y * 7;
      int ab = (y * 9 + x) * 8;
      f32x4 acc = {0.f, 0.f, 0.f, 0.f};
      #pragma unroll
      for (int g = 0; g < 5; ++g) {
        uint4 bv = *(const uint4*)(NA + ab + roff[g]);
        acc = mfma16(af[g], bv, acc);
      }
      if (px0 < 49 && (cot == 0 || s_ < 2)) {
        int ob = (y * 7 + x) * 12 + cot * 8;
        NB[ob + 2 * s_] = pack_relu(acc[0], acc[1]);
        NB[ob + 2 * s_ + 1] = pack_relu(acc[2], acc[3]);
      }
    }
  }
  __syncthreads();

  // P14: stage wd; pool3 3x3 s2 p0: a5[7][7][12] -> p3 planar [12cp][9]
  for (int i = t; i < 1080; i += 256) WS[i] = wp[WDF + i];
  for (int q = u; q < 108; q += 128) {
    int cp = q % 12, pxq = q / 12;
    int y = pxq / 3, x = pxq % 3;
    const u32* basep = SB + ((2 * y) * 7 + 2 * x) * 12 + cp;
    u32 m = 0;
    #pragma unroll
    for (int jj = 0; jj < 3; ++jj)
      #pragma unroll
      for (int kk = 0; kk < 3; ++kk) m = max2(m, basep[(jj * 7 + kk) * 12]);
    SA[cp * 9 + pxq] = m;
  }
  __syncthreads();

  // P15: dense partials: 2 img x 10 outs x 12 ci-pair chunks of 9 px
  if (t < 240) {
    int im = t / 120, r = t % 120, o = r / 12, c = r % 12;
    const u32* p3 = smem + im * AR;
    const u32* wrow = WS + o * 108 + c * 9;
    float acc = 0.f;
    #pragma unroll
    for (int s = 0; s < 9; ++s) acc = dot2(p3[c * 9 + s], wrow[s], acc);
    ((float*)(smem + im * AR))[128 + o * 12 + c] = acc;
  }
  __syncthreads();
  if (t < 20) {
    int im = t / 10, o = t % 10;
    const float* par = (const float*)(smem + im * AR) + 128 + o * 12;
    float s = 0.f;
    #pragma unroll
    for (int c = 0; c < 12; ++c) s += par[c];
    out[((long long)blockIdx.x * 2 + im) * 10 + o] = s;
  }
}

extern "C" void kernel_launch(void* const* d_in, const int* in_sizes, int n_in,
                              void* d_out, int out_size, void* d_ws, size_t ws_size,
                              hipStream_t stream) {
  const float* in = (const float*)d_in[0];
  const float* w1 = (const float*)d_in[1];
  const float* w2 = (const float*)d_in[2];
  const float* w3 = (const float*)d_in[3];
  const float* w4 = (const float*)d_in[4];
  const float* w5 = (const float*)d_in[5];
  const float* wd = (const float*)d_in[6];
  u32* wp = (u32*)d_ws;
  float* out = (float*)d_out;
  int B = in_sizes[0] / 784;

  prep_weights<<<(WTOT + 255) / 256, 256, 0, stream>>>(w2, w3, w4, w5, wd, wp);
  mnist_fused<<<B / 2, 256, 0, stream>>>(in, w1, wp, out);
}

// Round 9
// 262.427 us; speedup vs baseline: 2.9911x; 1.2800x over previous
//
#include <hip/hip_runtime.h>
#include <hip/hip_bf16.h>

typedef _Float16 half2v __attribute__((ext_vector_type(2)));
typedef _Float16 f16x8 __attribute__((ext_vector_type(8)));
typedef float f32x4 __attribute__((ext_vector_type(4)));
typedef unsigned int u32;

__device__ __forceinline__ float dot2(u32 a, u32 b, float c) {
  float d;
  asm("v_dot2_f32_f16 %0, %1, %2, %3" : "=v"(d) : "v"(a), "v"(b), "v"(c));
  return d;
}
__device__ __forceinline__ u32 pkrtz(float a, float b) {
  return __builtin_bit_cast(u32, __builtin_amdgcn_cvt_pkrtz(a, b));
}
__device__ __forceinline__ u32 pack_relu(float a, float b) {
  return pkrtz(fmaxf(a, 0.0f), fmaxf(b, 0.0f));
}
__device__ __forceinline__ u32 max2(u32 a, u32 b) {
  half2v x = __builtin_bit_cast(half2v, a);
  half2v y = __builtin_bit_cast(half2v, b);
  x.x = (y.x > x.x) ? y.x : x.x;
  x.y = (y.y > x.y) ? y.y : x.y;
  return __builtin_bit_cast(u32, x);
}
__device__ __forceinline__ int imin(int a, int b) { return a < b ? a : b; }

// ---- weight A-fragment layout in d_ws (u32 = f16 pair) -----------------
// A-frag for mfma_f32_16x16x32_f16: lane l holds A[row=l&15][k=8*(l>>4)+j].
// Stored per layer per k-group g: [g][lane][4 u32].
#define W1F 0      // conv1: 2 g. k-perm: pair p=k>>1 -> ky=p>>2, kx=(p&3)*2+(k&1)
#define W2F 512    // conv2: 4 g  (k = tap*4+ci)
#define W3F 1536   // conv3: 3 g  (k = tap*8+ci)
#define W4F 2304   // conv4: 5 g  (k = tap*16+ci)
#define W5F 3584   // conv5: 2 cot x 5 g
#define WDF 6144   // dense: [10][12cp][9px] pairs
#define WTOT 7224

__global__ void __launch_bounds__(256) prep_weights(
    const float* __restrict__ w1, const float* __restrict__ w2,
    const float* __restrict__ w3, const float* __restrict__ w4,
    const float* __restrict__ w5, const float* __restrict__ wd,
    u32* __restrict__ wp) {
  int i = threadIdx.x + blockIdx.x * 256;
  if (i < 512) {  // conv1 A-frags: w1 [3co][7][7]
    int g = i >> 8, rem = i & 255, l = rem >> 2, r = rem & 3;
    int s = l >> 4, co = l & 15;
    float v[2];
    #pragma unroll
    for (int e = 0; e < 2; ++e) {
      int k = g * 32 + 8 * s + 2 * r + e;
      int p = k >> 1;
      int ky = p >> 2, kx = ((p & 3) << 1) + (k & 1);
      v[e] = (co < 3 && ky < 7 && kx < 7) ? w1[co * 49 + ky * 7 + kx] : 0.0f;
    }
    wp[W1F + i] = pkrtz(v[0], v[1]);
  } else if (i < 1536) {  // conv2: w2 [8co][3ci][5][5]
    int q = i - W2F;
    int g = q >> 8, rem = q & 255, l = rem >> 2, r = rem & 3;
    int s = l >> 4, co = l & 15;
    float v[2];
    #pragma unroll
    for (int e = 0; e < 2; ++e) {
      int k = g * 32 + 8 * s + 2 * r + e;
      int t = k >> 2, ci = k & 3;
      v[e] = (co < 8 && ci < 3 && t < 25) ? w2[co * 75 + ci * 25 + t] : 0.0f;
    }
    wp[W2F + q] = pkrtz(v[0], v[1]);
  } else if (i < 2304) {  // conv3: w3 [10co][8ci][3][3]
    int q = i - W3F;
    int g = q >> 8, rem = q & 255, l = rem >> 2, r = rem & 3;
    int s = l >> 4, co = l & 15;
    float v[2];
    #pragma unroll
    for (int e = 0; e < 2; ++e) {
      int k = g * 32 + 8 * s + 2 * r + e;
      int t = k >> 3, ci = k & 7;
      v[e] = (co < 10 && t < 9) ? w3[co * 72 + ci * 9 + t] : 0.0f;
    }
    wp[W3F + q] = pkrtz(v[0], v[1]);
  } else if (i < 3584) {  // conv4: w4 [16co][10ci][3][3]
    int q = i - W4F;
    int g = q >> 8, rem = q & 255, l = rem >> 2, r = rem & 3;
    int s = l >> 4, co = l & 15;
    float v[2];
    #pragma unroll
    for (int e = 0; e < 2; ++e) {
      int k = g * 32 + 8 * s + 2 * r + e;
      int t = k >> 4, ci = k & 15;
      v[e] = (ci < 10 && t < 9) ? w4[co * 90 + ci * 9 + t] : 0.0f;
    }
    wp[W4F + q] = pkrtz(v[0], v[1]);
  } else if (i < 6144) {  // conv5: w5 [24co][16ci][3][3], 2 co-tiles
    int q = i - W5F;
    int cot = q / 1280, q2 = q % 1280;
    int g = q2 >> 8, rem = q2 & 255, l = rem >> 2, r = rem & 3;
    int s = l >> 4, co = cot * 16 + (l & 15);
    float v[2];
    #pragma unroll
    for (int e = 0; e < 2; ++e) {
      int k = g * 32 + 8 * s + 2 * r + e;
      int t = k >> 4, ci = k & 15;
      v[e] = (co < 24 && t < 9) ? w5[co * 144 + ci * 9 + t] : 0.0f;
    }
    wp[W5F + q] = pkrtz(v[0], v[1]);
  } else if (i < WTOT) {  // dense: wd [10][216], k = ci*9 + px
    int j = i - WDF;
    int o = j / 108, r = j % 108, cp = r / 9, s = r % 9;
    wp[WDF + j] = pkrtz(wd[o * 216 + (2 * cp) * 9 + s],
                        wd[o * 216 + (2 * cp + 1) * 9 + s]);
  }
}

// ---- fused network: 2 images per 256-thread block ----------------------
// Channels-last f16 activations (u32 = ci-pair). Per image:
//  Arena A (3600): IN dual-parity f16 [2][35][20](1400) -> a2[30][30][8ci](3600)
//    -> a3[16][16][16ci](2048) -> p2[9][9][16ci](648) -> p3(108)+partials
//  Arena B (2048): a1[32][32][4ci](2048) -> p1[16][16][8ci](1024)
//    -> a4[16][16][16ci](2048) -> a5[7][7][24ci](588)
#define AR_A 3600
#define AR_B 2048
#define AR (AR_A + AR_B)
#define WSOFF (2 * AR)
#define SMEMN (2 * AR + 1080)  // 12376 u32 = 49504 B -> 3 blocks/CU

__device__ __forceinline__ f32x4 mfma16(uint4 a, uint4 b, f32x4 c) {
  return __builtin_amdgcn_mfma_f32_16x16x32_f16(
      __builtin_bit_cast(f16x8, a), __builtin_bit_cast(f16x8, b), c, 0, 0, 0);
}

__global__ void __launch_bounds__(256) mnist_fused(
    const float* __restrict__ in, const u32* __restrict__ wp,
    float* __restrict__ out) {
  __shared__ __align__(16) u32 smem[SMEMN];
  const int t = threadIdx.x;
  const int u = t & 127;
  const int img = t >> 7;
  const int lane = t & 63;
  const int wid = t >> 6;
  const long long b = (long long)blockIdx.x * 2 + img;
  u32* SA = smem + img * AR;
  u32* SB = SA + AR_A;
  u32* WS = smem + WSOFF;

  // per-lane mfma identities (col n -> (pixel-group, image))
  const int s_ = lane >> 4, n_ = lane & 15;
  const int nimg = n_ & 1, pxg = n_ >> 1;
  u32* NA = smem + nimg * AR;
  u32* NB = NA + AR_A;

  // P0: zero IN (both parities + pad row) + a1
  {
    uint4 z = {0, 0, 0, 0};
    uint4* za = (uint4*)SA;
    uint4* zb = (uint4*)SB;
    for (int i = u; i < 350; i += 128) za[i] = z;
    for (int i = u; i < 512; i += 128) zb[i] = z;
  }
  __syncthreads();

  // P1: stage input as f16, dual parity. H0[sy*40+sx]=v, H1[sy*40+sx-1]=v
  {
    const float* inb = in + b * 784;
    _Float16* H0 = (_Float16*)SA;
    _Float16* H1 = (_Float16*)(SA + 700);
    for (int p = u; p < 784; p += 128) {
      int y = p / 28, x = p % 28;
      _Float16 h = (_Float16)inb[p];
      int sy = y + 3, sx = x + 3;
      H0[sy * 40 + sx] = h;
      H1[sy * 40 + sx - 1] = h;
    }
  }
  __syncthreads();

  // P2: conv1 MFMA. M=co3(pad16), N=(8px,2img), K=49->64 (2 g)
  // lane (s_,g) reads input row y+4g+s_, 4 contiguous u32 at parity(x)
  {
    uint4 af[2];
    const uint4* wq = (const uint4*)(wp + W1F);
    af[0] = wq[lane];
    af[1] = wq[64 + lane];
    #pragma unroll 1
    for (int j = wid; j < 98; j += 4) {
      int px = j * 8 + pxg;
      int y = px / 28, x = px % 28;
      const u32* base = NA + ((x & 1) ? 700 : 0) + (x >> 1);
      f32x4 acc = {0.f, 0.f, 0.f, 0.f};
      #pragma unroll
      for (int g = 0; g < 2; ++g) {
        const u32* rp = base + (y + 4 * g + s_) * 20;
        uint4 bv = {rp[0], rp[1], rp[2], rp[3]};
        acc = mfma16(af[g], bv, acc);
      }
      if (s_ == 0) {
        int ob = ((y + 2) * 32 + (x + 2)) * 2;
        NB[ob] = pack_relu(acc[0], acc[1]);
        NB[ob + 1] = pack_relu(acc[2], acc[3]);
      }
    }
  }
  __syncthreads();

  // P3: zero a2
  {
    uint4 z = {0, 0, 0, 0};
    uint4* za = (uint4*)SA;
    for (int i = u; i < 900; i += 128) za[i] = z;
  }
  __syncthreads();

  // P4: conv2 MFMA. M=co8, K=25taps*4ci -> 4 g
  {
    uint4 af[4];
    const uint4* wq = (const uint4*)(wp + W2F);
    #pragma unroll
    for (int g = 0; g < 4; ++g) af[g] = wq[g * 64 + lane];
    int ro0[4], ro1[4];
    #pragma unroll
    for (int g = 0; g < 4; ++g) {
      int t0 = imin(g * 8 + 2 * s_, 24), t1 = imin(g * 8 + 2 * s_ + 1, 24);
      ro0[g] = ((t0 / 5) * 32 + t0 % 5) * 2;
      ro1[g] = ((t1 / 5) * 32 + t1 % 5) * 2;
    }
    #pragma unroll 1
    for (int j = wid; j < 98; j += 4) {
      int px = j * 8 + pxg;
      int y = px / 28, x = px % 28;
      int ab = (y * 32 + x) * 2;
      f32x4 acc = {0.f, 0.f, 0.f, 0.f};
      #pragma unroll
      for (int g = 0; g < 4; ++g) {
        uint2 lo = *(const uint2*)(NB + ab + ro0[g]);
        uint2 hi = *(const uint2*)(NB + ab + ro1[g]);
        uint4 bv = {lo.x, lo.y, hi.x, hi.y};
        acc = mfma16(af[g], bv, acc);
      }
      if (s_ < 2) {
        int ob = ((y + 1) * 30 + (x + 1)) * 4;
        NA[ob + 2 * s_] = pack_relu(acc[0], acc[1]);
        NA[ob + 2 * s_ + 1] = pack_relu(acc[2], acc[3]);
      }
    }
  }
  __syncthreads();

  // P5: zero p1
  {
    uint4 z = {0, 0, 0, 0};
    uint4* zb = (uint4*)SB;
    for (int i = u; i < 256; i += 128) zb[i] = z;
  }
  __syncthreads();

  // P6: pool1 3x3 s2 p1: a2[30][30][4] -> p1[16][16][4], uint2 lanes
  for (int q = u; q < 392; q += 128) {
    int cpp = q & 1, pxq = q >> 1;
    int y = pxq / 14, x = pxq % 14;
    const u32* basep = SA + ((2 * y) * 30 + 2 * x) * 4 + cpp * 2;
    u32 m0 = 0, m1 = 0;
    #pragma unroll
    for (int jj = 0; jj < 3; ++jj)
      #pragma unroll
      for (int kk = 0; kk < 3; ++kk) {
        uint2 v = *(const uint2*)(basep + (jj * 30 + kk) * 4);
        m0 = max2(m0, v.x);
        m1 = max2(m1, v.y);
      }
    uint2 r = {m0, m1};
    *(uint2*)(SB + ((y + 1) * 16 + (x + 1)) * 4 + cpp * 2) = r;
  }
  __syncthreads();

  // P7: zero a3
  {
    uint4 z = {0, 0, 0, 0};
    uint4* za = (uint4*)SA;
    for (int i = u; i < 512; i += 128) za[i] = z;
  }
  __syncthreads();

  // P8: conv3 MFMA. M=co10, K=9taps*8ci -> 3 g
  {
    uint4 af[3];
    const uint4* wq = (const uint4*)(wp + W3F);
    #pragma unroll
    for (int g = 0; g < 3; ++g) af[g] = wq[g * 64 + lane];
    int roff[3];
    #pragma unroll
    for (int g = 0; g < 3; ++g) {
      int tt = imin(g * 4 + s_, 8);
      roff[g] = ((tt / 3) * 16 + tt % 3) * 4;
    }
    #pragma unroll 1
    for (int j = wid; j < 25; j += 4) {
      int px0 = j * 8 + pxg;
      int px = imin(px0, 195);
      int y = px / 14, x = px % 14;
      int ab = (y * 16 + x) * 4;
      f32x4 acc = {0.f, 0.f, 0.f, 0.f};
      #pragma unroll
      for (int g = 0; g < 3; ++g) {
        uint4 bv = *(const uint4*)(NB + ab + roff[g]);
        acc = mfma16(af[g], bv, acc);
      }
      if (px0 < 196) {
        int ob = ((y + 1) * 16 + (x + 1)) * 8;
        int cp0 = 2 * s_, cp1 = 2 * s_ + 1;
        u32 p0 = pack_relu(acc[0], acc[1]);
        u32 p1v = pack_relu(acc[2], acc[3]);
        if (cp0 < 5) NA[ob + cp0] = p0;
        if (cp1 < 5) NA[ob + cp1] = p1v;
      }
    }
  }
  __syncthreads();

  // P9: zero a4
  {
    uint4 z = {0, 0, 0, 0};
    uint4* zb = (uint4*)SB;
    for (int i = u; i < 512; i += 128) zb[i] = z;
  }
  __syncthreads();

  // P10: conv4 MFMA. M=co16, K=9taps*16ci -> 5 g
  {
    uint4 af[5];
    const uint4* wq = (const uint4*)(wp + W4F);
    #pragma unroll
    for (int g = 0; g < 5; ++g) af[g] = wq[g * 64 + lane];
    int roff[5];
    #pragma unroll
    for (int g = 0; g < 5; ++g) {
      int tt = imin(g * 2 + (s_ >> 1), 8);
      roff[g] = ((tt / 3) * 16 + tt % 3) * 8 + (s_ & 1) * 4;
    }
    #pragma unroll 1
    for (int j = wid; j < 25; j += 4) {
      int px0 = j * 8 + pxg;
      int px = imin(px0, 195);
      int y = px / 14, x = px % 14;
      int ab = (y * 16 + x) * 8;
      f32x4 acc = {0.f, 0.f, 0.f, 0.f};
      #pragma unroll
      for (int g = 0; g < 5; ++g) {
        uint4 bv = *(const uint4*)(NA + ab + roff[g]);
        acc = mfma16(af[g], bv, acc);
      }
      if (px0 < 196) {
        int ob = ((y + 1) * 16 + (x + 1)) * 8;
        NB[ob + 2 * s_] = pack_relu(acc[0], acc[1]);
        NB[ob + 2 * s_ + 1] = pack_relu(acc[2], acc[3]);
      }
    }
  }
  __syncthreads();

  // P11: zero p2
  {
    uint4 z = {0, 0, 0, 0};
    uint4* za = (uint4*)SA;
    for (int i = u; i < 162; i += 128) za[i] = z;
  }
  __syncthreads();

  // P12: pool2 3x3 s2 p1: a4[16][16][8] -> p2[9][9][8], uint4 lanes
  if (u < 98) {
    int cpq = u & 1, pxq = u >> 1;
    int y = pxq / 7, x = pxq % 7;
    const u32* basep = SB + ((2 * y) * 16 + 2 * x) * 8 + cpq * 4;
    u32 m0 = 0, m1 = 0, m2 = 0, m3 = 0;
    #pragma unroll
    for (int jj = 0; jj < 3; ++jj)
      #pragma unroll
      for (int kk = 0; kk < 3; ++kk) {
        uint4 v = *(const uint4*)(basep + (jj * 16 + kk) * 8);
        m0 = max2(m0, v.x);
        m1 = max2(m1, v.y);
        m2 = max2(m2, v.z);
        m3 = max2(m3, v.w);
      }
    uint4 r = {m0, m1, m2, m3};
    *(uint4*)(SA + ((y + 1) * 9 + (x + 1)) * 8 + cpq * 4) = r;
  }
  __syncthreads();

  // P13: conv5 MFMA. M=co (2 tiles of 16), K=9taps*16ci -> 5 g
  {
    int roff[5];
    #pragma unroll
    for (int g = 0; g < 5; ++g) {
      int tt = imin(g * 2 + (s_ >> 1), 8);
      roff[g] = ((tt / 3) * 9 + tt % 3) * 8 + (s_ & 1) * 4;
    }
    #pragma unroll 1
    for (int j = wid; j < 14; j += 4) {
      int cot = j / 7, pj = j - cot * 7;
      uint4 af[5];
      const uint4* wq = (const uint4*)(wp + W5F + cot * 1280);
      #pragma unroll
      for (int g = 0; g < 5; ++g) af[g] = wq[g * 64 + lane];
      int px0 = pj * 8 + pxg;
      int px = imin(px0, 48);
      int y = px / 7, x = px - y * 7;
      int ab = (y * 9 + x) * 8;
      f32x4 acc = {0.f, 0.f, 0.f, 0.f};
      #pragma unroll
      for (int g = 0; g < 5; ++g) {
        uint4 bv = *(const uint4*)(NA + ab + roff[g]);
        acc = mfma16(af[g], bv, acc);
      }
      if (px0 < 49 && (cot == 0 || s_ < 2)) {
        int ob = (y * 7 + x) * 12 + cot * 8;
        NB[ob + 2 * s_] = pack_relu(acc[0], acc[1]);
        NB[ob + 2 * s_ + 1] = pack_relu(acc[2], acc[3]);
      }
    }
  }
  __syncthreads();

  // P14: stage wd; pool3 3x3 s2 p0: a5[7][7][12] -> p3 planar [12cp][9]
  for (int i = t; i < 1080; i += 256) WS[i] = wp[WDF + i];
  for (int q = u; q < 108; q += 128) {
    int cp = q % 12, pxq = q / 12;
    int y = pxq / 3, x = pxq % 3;
    const u32* basep = SB + ((2 * y) * 7 + 2 * x) * 12 + cp;
    u32 m = 0;
    #pragma unroll
    for (int jj = 0; jj < 3; ++jj)
      #pragma unroll
      for (int kk = 0; kk < 3; ++kk) m = max2(m, basep[(jj * 7 + kk) * 12]);
    SA[cp * 9 + pxq] = m;
  }
  __syncthreads();

  // P15: dense partials: 2 img x 10 outs x 12 ci-pair chunks of 9 px
  if (t < 240) {
    int im = t / 120, r = t % 120, o = r / 12, c = r % 12;
    const u32* p3 = smem + im * AR;
    const u32* wrow = WS + o * 108 + c * 9;
    float acc = 0.f;
    #pragma unroll
    for (int s = 0; s < 9; ++s) acc = dot2(p3[c * 9 + s], wrow[s], acc);
    ((float*)(smem + im * AR))[128 + o * 12 + c] = acc;
  }
  __syncthreads();
  if (t < 20) {
    int im = t / 10, o = t % 10;
    const float* par = (const float*)(smem + im * AR) + 128 + o * 12;
    float s = 0.f;
    #pragma unroll
    for (int c = 0; c < 12; ++c) s += par[c];
    out[((long long)blockIdx.x * 2 + im) * 10 + o] = s;
  }
}

extern "C" void kernel_launch(void* const* d_in, const int* in_sizes, int n_in,
                              void* d_out, int out_size, void* d_ws, size_t ws_size,
                              hipStream_t stream) {
  const float* in = (const float*)d_in[0];
  const float* w1 = (const float*)d_in[1];
  const float* w2 = (const float*)d_in[2];
  const float* w3 = (const float*)d_in[3];
  const float* w4 = (const float*)d_in[4];
  const float* w5 = (const float*)d_in[5];
  const float* wd = (const float*)d_in[6];
  u32* wp = (u32*)d_ws;
  float* out = (float*)d_out;
  int B = in_sizes[0] / 784;

  prep_weights<<<(WTOT + 255) / 256, 256, 0, stream>>>(w1, w2, w3, w4, w5, wd, wp);
  mnist_fused<<<B / 2, 256, 0, stream>>>(in, wp, out);
}

// Round 10
// 259.374 us; speedup vs baseline: 3.0263x; 1.0118x over previous
//
#include <hip/hip_runtime.h>
#include <hip/hip_bf16.h>

typedef _Float16 half2v __attribute__((ext_vector_type(2)));
typedef _Float16 f16x8 __attribute__((ext_vector_type(8)));
typedef float f32x4 __attribute__((ext_vector_type(4)));
typedef unsigned int u32;

__device__ __forceinline__ float dot2(u32 a, u32 b, float c) {
  float d;
  asm("v_dot2_f32_f16 %0, %1, %2, %3" : "=v"(d) : "v"(a), "v"(b), "v"(c));
  return d;
}
__device__ __forceinline__ u32 pkrtz(float a, float b) {
  return __builtin_bit_cast(u32, __builtin_amdgcn_cvt_pkrtz(a, b));
}
// relu on packed f16 pair: 2 VALU (cvt_pkrtz + pk_max vs 0)
__device__ __forceinline__ u32 pack_relu(float a, float b) {
  u32 p = pkrtz(a, b);
  u32 r;
  asm("v_pk_max_f16 %0, %1, 0" : "=v"(r) : "v"(p));
  return r;
}
__device__ __forceinline__ u32 max2(u32 a, u32 b) {
  half2v x = __builtin_bit_cast(half2v, a);
  half2v y = __builtin_bit_cast(half2v, b);
  x.x = (y.x > x.x) ? y.x : x.x;
  x.y = (y.y > x.y) ? y.y : x.y;
  return __builtin_bit_cast(u32, x);
}
__device__ __forceinline__ int imin(int a, int b) { return a < b ? a : b; }

// ---- weight A-fragment layout in d_ws (u32 = f16 pair) -----------------
#define W1F 0      // conv1: 2 g. k-perm: pair p=k>>1 -> ky=p>>2, kx=(p&3)*2+(k&1)
#define W2F 512    // conv2: 4 g  (k = tap*4+ci)
#define W3F 1536   // conv3: 3 g  (k = tap*8+ci)
#define W4F 2304   // conv4: 5 g  (k = tap*16+ci)
#define W5F 3584   // conv5: 2 cot x 5 g
#define WDF 6144   // dense: [10][12cp][9px] pairs
#define WTOT 7224

__global__ void __launch_bounds__(256) prep_weights(
    const float* __restrict__ w1, const float* __restrict__ w2,
    const float* __restrict__ w3, const float* __restrict__ w4,
    const float* __restrict__ w5, const float* __restrict__ wd,
    u32* __restrict__ wp) {
  int i = threadIdx.x + blockIdx.x * 256;
  if (i < 512) {  // conv1 A-frags: w1 [3co][7][7]
    int g = i >> 8, rem = i & 255, l = rem >> 2, r = rem & 3;
    int s = l >> 4, co = l & 15;
    float v[2];
    #pragma unroll
    for (int e = 0; e < 2; ++e) {
      int k = g * 32 + 8 * s + 2 * r + e;
      int p = k >> 1;
      int ky = p >> 2, kx = ((p & 3) << 1) + (k & 1);
      v[e] = (co < 3 && ky < 7 && kx < 7) ? w1[co * 49 + ky * 7 + kx] : 0.0f;
    }
    wp[W1F + i] = pkrtz(v[0], v[1]);
  } else if (i < 1536) {  // conv2: w2 [8co][3ci][5][5]
    int q = i - W2F;
    int g = q >> 8, rem = q & 255, l = rem >> 2, r = rem & 3;
    int s = l >> 4, co = l & 15;
    float v[2];
    #pragma unroll
    for (int e = 0; e < 2; ++e) {
      int k = g * 32 + 8 * s + 2 * r + e;
      int t = k >> 2, ci = k & 3;
      v[e] = (co < 8 && ci < 3 && t < 25) ? w2[co * 75 + ci * 25 + t] : 0.0f;
    }
    wp[W2F + q] = pkrtz(v[0], v[1]);
  } else if (i < 2304) {  // conv3: w3 [10co][8ci][3][3]
    int q = i - W3F;
    int g = q >> 8, rem = q & 255, l = rem >> 2, r = rem & 3;
    int s = l >> 4, co = l & 15;
    float v[2];
    #pragma unroll
    for (int e = 0; e < 2; ++e) {
      int k = g * 32 + 8 * s + 2 * r + e;
      int t = k >> 3, ci = k & 7;
      v[e] = (co < 10 && t < 9) ? w3[co * 72 + ci * 9 + t] : 0.0f;
    }
    wp[W3F + q] = pkrtz(v[0], v[1]);
  } else if (i < 3584) {  // conv4: w4 [16co][10ci][3][3]
    int q = i - W4F;
    int g = q >> 8, rem = q & 255, l = rem >> 2, r = rem & 3;
    int s = l >> 4, co = l & 15;
    float v[2];
    #pragma unroll
    for (int e = 0; e < 2; ++e) {
      int k = g * 32 + 8 * s + 2 * r + e;
      int t = k >> 4, ci = k & 15;
      v[e] = (ci < 10 && t < 9) ? w4[co * 90 + ci * 9 + t] : 0.0f;
    }
    wp[W4F + q] = pkrtz(v[0], v[1]);
  } else if (i < 6144) {  // conv5: w5 [24co][16ci][3][3], 2 co-tiles
    int q = i - W5F;
    int cot = q / 1280, q2 = q % 1280;
    int g = q2 >> 8, rem = q2 & 255, l = rem >> 2, r = rem & 3;
    int s = l >> 4, co = cot * 16 + (l & 15);
    float v[2];
    #pragma unroll
    for (int e = 0; e < 2; ++e) {
      int k = g * 32 + 8 * s + 2 * r + e;
      int t = k >> 4, ci = k & 15;
      v[e] = (co < 24 && t < 9) ? w5[co * 144 + ci * 9 + t] : 0.0f;
    }
    wp[W5F + q] = pkrtz(v[0], v[1]);
  } else if (i < WTOT) {  // dense: wd [10][216], k = ci*9 + px
    int j = i - WDF;
    int o = j / 108, r = j % 108, cp = r / 9, s = r % 9;
    wp[WDF + j] = pkrtz(wd[o * 216 + (2 * cp) * 9 + s],
                        wd[o * 216 + (2 * cp + 1) * 9 + s]);
  }
}

// ---- fused network: 2 images per 256-thread block ----------------------
// Channels-last f16 activations (u32 = ci-pair). Per image:
//  Arena A (3600): IN dual-parity f16 [2][35][20](1400) -> a2[30][30][8ci](3600)
//    -> a3[16][16][16ci](2048) -> p2[9][9][16ci](648) -> p3(108)+partials
//  Arena B (2048): a1[32][32][4ci](2048) -> p1[16][16][8ci](1024)
//    -> a4[16][16][16ci](2048) -> a5[7][7][24ci](588)
#define AR_A 3600
#define AR_B 2048
#define AR (AR_A + AR_B)
#define WSOFF (2 * AR)
#define SMEMN (2 * AR + 1080)  // 12376 u32 = 49504 B -> 3 blocks/CU

__device__ __forceinline__ f32x4 mfma16(uint4 a, uint4 b, f32x4 c) {
  return __builtin_amdgcn_mfma_f32_16x16x32_f16(
      __builtin_bit_cast(f16x8, a), __builtin_bit_cast(f16x8, b), c, 0, 0, 0);
}

__global__ void __launch_bounds__(256) mnist_fused(
    const float* __restrict__ in, const u32* __restrict__ wp,
    float* __restrict__ out) {
  __shared__ __align__(16) u32 smem[SMEMN];
  const int t = threadIdx.x;
  const int u = t & 127;
  const int img = t >> 7;
  const int lane = t & 63;
  const int wid = t >> 6;
  const long long b = (long long)blockIdx.x * 2 + img;
  u32* SA = smem + img * AR;
  u32* SB = SA + AR_A;
  u32* WS = smem + WSOFF;

  // per-lane mfma identities (col n -> (pixel-group, image))
  const int s_ = lane >> 4, n_ = lane & 15;
  const int nimg = n_ & 1, pxg = n_ >> 1;
  u32* NA = smem + nimg * AR;
  u32* NB = NA + AR_A;

  // P0: zero IN (both parities + pad rows) + a1
  {
    uint4 z = {0, 0, 0, 0};
    uint4* za = (uint4*)SA;
    uint4* zb = (uint4*)SB;
    for (int i = u; i < 350; i += 128) za[i] = z;
    for (int i = u; i < 512; i += 128) zb[i] = z;
  }
  __syncthreads();

  // P1: stage input as f16, dual parity. H0[sy*40+sx]=v, H1[sy*40+sx-1]=v
  {
    const float* inb = in + b * 784;
    _Float16* H0 = (_Float16*)SA;
    _Float16* H1 = (_Float16*)(SA + 700);
    for (int p = u; p < 784; p += 128) {
      int y = p / 28, x = p % 28;
      _Float16 h = (_Float16)inb[p];
      int sy = y + 3, sx = x + 3;
      H0[sy * 40 + sx] = h;
      H1[sy * 40 + sx - 1] = h;
    }
  }
  __syncthreads();

  // P2: conv1 MFMA, double-tile (16 px/j). y=j>>1, x=(j&1)*16+pxg, x2=x+8
  {
    uint4 af[2];
    const uint4* wq = (const uint4*)(wp + W1F);
    af[0] = wq[lane];
    af[1] = wq[64 + lane];
    #pragma unroll 1
    for (int j = wid; j < 56; j += 4) {
      int y = j >> 1;
      int x = ((j & 1) << 4) + pxg;
      const u32* base = NA + ((x & 1) ? 700 : 0) + (x >> 1);
      f32x4 acc0 = {0.f, 0.f, 0.f, 0.f};
      f32x4 acc1 = {0.f, 0.f, 0.f, 0.f};
      #pragma unroll
      for (int g = 0; g < 2; ++g) {
        const u32* rp = base + (y + 4 * g + s_) * 20;
        uint4 b0 = {rp[0], rp[1], rp[2], rp[3]};
        uint4 b1 = {rp[4], rp[5], rp[6], rp[7]};
        acc0 = mfma16(af[g], b0, acc0);
        acc1 = mfma16(af[g], b1, acc1);
      }
      if (s_ == 0) {
        int ob = ((y + 2) * 32 + (x + 2)) * 2;
        NB[ob] = pack_relu(acc0[0], acc0[1]);
        NB[ob + 1] = pack_relu(acc0[2], acc0[3]);
        if (x + 8 < 28) {
          NB[ob + 16] = pack_relu(acc1[0], acc1[1]);
          NB[ob + 17] = pack_relu(acc1[2], acc1[3]);
        }
      }
    }
  }
  __syncthreads();

  // P3: zero a2
  {
    uint4 z = {0, 0, 0, 0};
    uint4* za = (uint4*)SA;
    for (int i = u; i < 900; i += 128) za[i] = z;
  }
  __syncthreads();

  // P4: conv2 MFMA, double-tile. K=25taps*4ci -> 4 g
  {
    uint4 af[4];
    const uint4* wq = (const uint4*)(wp + W2F);
    #pragma unroll
    for (int g = 0; g < 4; ++g) af[g] = wq[g * 64 + lane];
    int ro0[4], ro1[4];
    #pragma unroll
    for (int g = 0; g < 4; ++g) {
      int t0 = imin(g * 8 + 2 * s_, 24), t1 = imin(g * 8 + 2 * s_ + 1, 24);
      ro0[g] = ((t0 / 5) * 32 + t0 % 5) * 2;
      ro1[g] = ((t1 / 5) * 32 + t1 % 5) * 2;
    }
    #pragma unroll 1
    for (int j = wid; j < 56; j += 4) {
      int y = j >> 1;
      int x = ((j & 1) << 4) + pxg;
      int ab = (y * 32 + x) * 2;
      f32x4 acc0 = {0.f, 0.f, 0.f, 0.f};
      f32x4 acc1 = {0.f, 0.f, 0.f, 0.f};
      #pragma unroll
      for (int g = 0; g < 4; ++g) {
        uint2 lo0 = *(const uint2*)(NB + ab + ro0[g]);
        uint2 hi0 = *(const uint2*)(NB + ab + ro1[g]);
        uint4 b0 = {lo0.x, lo0.y, hi0.x, hi0.y};
        acc0 = mfma16(af[g], b0, acc0);
        uint2 lo1 = *(const uint2*)(NB + ab + 16 + ro0[g]);
        uint2 hi1 = *(const uint2*)(NB + ab + 16 + ro1[g]);
        uint4 b1 = {lo1.x, lo1.y, hi1.x, hi1.y};
        acc1 = mfma16(af[g], b1, acc1);
      }
      if (s_ < 2) {
        int ob = ((y + 1) * 30 + (x + 1)) * 4;
        NA[ob + 2 * s_] = pack_relu(acc0[0], acc0[1]);
        NA[ob + 2 * s_ + 1] = pack_relu(acc0[2], acc0[3]);
        if (x + 8 < 28) {
          NA[ob + 32 + 2 * s_] = pack_relu(acc1[0], acc1[1]);
          NA[ob + 32 + 2 * s_ + 1] = pack_relu(acc1[2], acc1[3]);
        }
      }
    }
  }
  __syncthreads();

  // P5: zero p1
  {
    uint4 z = {0, 0, 0, 0};
    uint4* zb = (uint4*)SB;
    for (int i = u; i < 256; i += 128) zb[i] = z;
  }
  __syncthreads();

  // P6: pool1 3x3 s2 p1: a2[30][30][4] -> p1[16][16][4], uint2 lanes
  for (int q = u; q < 392; q += 128) {
    int cpp = q & 1, pxq = q >> 1;
    int y = pxq / 14, x = pxq % 14;
    const u32* basep = SA + ((2 * y) * 30 + 2 * x) * 4 + cpp * 2;
    u32 m0 = 0, m1 = 0;
    #pragma unroll
    for (int jj = 0; jj < 3; ++jj)
      #pragma unroll
      for (int kk = 0; kk < 3; ++kk) {
        uint2 v = *(const uint2*)(basep + (jj * 30 + kk) * 4);
        m0 = max2(m0, v.x);
        m1 = max2(m1, v.y);
      }
    uint2 r = {m0, m1};
    *(uint2*)(SB + ((y + 1) * 16 + (x + 1)) * 4 + cpp * 2) = r;
  }
  __syncthreads();

  // P7: zero a3
  {
    uint4 z = {0, 0, 0, 0};
    uint4* za = (uint4*)SA;
    for (int i = u; i < 512; i += 128) za[i] = z;
  }
  __syncthreads();

  // P8: conv3 MFMA. no-div tiles: y=j>>1, x=(j&1)*8+pxg, mask x<14
  {
    uint4 af[3];
    const uint4* wq = (const uint4*)(wp + W3F);
    #pragma unroll
    for (int g = 0; g < 3; ++g) af[g] = wq[g * 64 + lane];
    int roff[3];
    #pragma unroll
    for (int g = 0; g < 3; ++g) {
      int tt = imin(g * 4 + s_, 8);
      roff[g] = ((tt / 3) * 16 + tt % 3) * 4;
    }
    #pragma unroll 1
    for (int j = wid; j < 28; j += 4) {
      int y = j >> 1;
      int x = ((j & 1) << 3) + pxg;
      int ab = (y * 16 + x) * 4;
      f32x4 acc = {0.f, 0.f, 0.f, 0.f};
      #pragma unroll
      for (int g = 0; g < 3; ++g) {
        uint4 bv = *(const uint4*)(NB + ab + roff[g]);
        acc = mfma16(af[g], bv, acc);
      }
      if (x < 14) {
        int ob = ((y + 1) * 16 + (x + 1)) * 8;
        int cp0 = 2 * s_, cp1 = 2 * s_ + 1;
        u32 p0 = pack_relu(acc[0], acc[1]);
        u32 p1v = pack_relu(acc[2], acc[3]);
        if (cp0 < 5) NA[ob + cp0] = p0;
        if (cp1 < 5) NA[ob + cp1] = p1v;
      }
    }
  }
  __syncthreads();

  // P9: zero a4
  {
    uint4 z = {0, 0, 0, 0};
    uint4* zb = (uint4*)SB;
    for (int i = u; i < 512; i += 128) zb[i] = z;
  }
  __syncthreads();

  // P10: conv4 MFMA. no-div tiles
  {
    uint4 af[5];
    const uint4* wq = (const uint4*)(wp + W4F);
    #pragma unroll
    for (int g = 0; g < 5; ++g) af[g] = wq[g * 64 + lane];
    int roff[5];
    #pragma unroll
    for (int g = 0; g < 5; ++g) {
      int tt = imin(g * 2 + (s_ >> 1), 8);
      roff[g] = ((tt / 3) * 16 + tt % 3) * 8 + (s_ & 1) * 4;
    }
    #pragma unroll 1
    for (int j = wid; j < 28; j += 4) {
      int y = j >> 1;
      int x = ((j & 1) << 3) + pxg;
      int ab = (y * 16 + x) * 8;
      f32x4 acc = {0.f, 0.f, 0.f, 0.f};
      #pragma unroll
      for (int g = 0; g < 5; ++g) {
        uint4 bv = *(const uint4*)(NA + ab + roff[g]);
        acc = mfma16(af[g], bv, acc);
      }
      if (x < 14) {
        int ob = ((y + 1) * 16 + (x + 1)) * 8;
        NB[ob + 2 * s_] = pack_relu(acc[0], acc[1]);
        NB[ob + 2 * s_ + 1] = pack_relu(acc[2], acc[3]);
      }
    }
  }
  __syncthreads();

  // P11: zero p2
  {
    uint4 z = {0, 0, 0, 0};
    uint4* za = (uint4*)SA;
    for (int i = u; i < 162; i += 128) za[i] = z;
  }
  __syncthreads();

  // P12: pool2 3x3 s2 p1: a4[16][16][8] -> p2[9][9][8], uint4 lanes
  if (u < 98) {
    int cpq = u & 1, pxq = u >> 1;
    int y = pxq / 7, x = pxq % 7;
    const u32* basep = SB + ((2 * y) * 16 + 2 * x) * 8 + cpq * 4;
    u32 m0 = 0, m1 = 0, m2 = 0, m3 = 0;
    #pragma unroll
    for (int jj = 0; jj < 3; ++jj)
      #pragma unroll
      for (int kk = 0; kk < 3; ++kk) {
        uint4 v = *(const uint4*)(basep + (jj * 16 + kk) * 8);
        m0 = max2(m0, v.x);
        m1 = max2(m1, v.y);
        m2 = max2(m2, v.z);
        m3 = max2(m3, v.w);
      }
    uint4 r = {m0, m1, m2, m3};
    *(uint4*)(SA + ((y + 1) * 9 + (x + 1)) * 8 + cpq * 4) = r;
  }
  __syncthreads();

  // P13: conv5 MFMA. no-div: cot=(j>6), y=pj, x=pxg, mask x<7
  {
    int roff[5];
    #pragma unroll
    for (int g = 0; g < 5; ++g) {
      int tt = imin(g * 2 + (s_ >> 1), 8);
      roff[g] = ((tt / 3) * 9 + tt % 3) * 8 + (s_ & 1) * 4;
    }
    #pragma unroll 1
    for (int j = wid; j < 14; j += 4) {
      int cot = j > 6 ? 1 : 0;
      int y = j - (cot ? 7 : 0);
      int x = pxg;
      uint4 af[5];
      const uint4* wq = (const uint4*)(wp + W5F + cot * 1280);
      #pragma unroll
      for (int g = 0; g < 5; ++g) af[g] = wq[g * 64 + lane];
      int ab = (y * 9 + x) * 8;
      f32x4 acc = {0.f, 0.f, 0.f, 0.f};
      #pragma unroll
      for (int g = 0; g < 5; ++g) {
        uint4 bv = *(const uint4*)(NA + ab + roff[g]);
        acc = mfma16(af[g], bv, acc);
      }
      if (x < 7 && (cot == 0 || s_ < 2)) {
        int ob = (y * 7 + x) * 12 + cot * 8;
        NB[ob + 2 * s_] = pack_relu(acc[0], acc[1]);
        NB[ob + 2 * s_ + 1] = pack_relu(acc[2], acc[3]);
      }
    }
  }
  __syncthreads();

  // P14: stage wd; pool3 3x3 s2 p0: a5[7][7][12] -> p3 planar [12cp][9]
  for (int i = t; i < 1080; i += 256) WS[i] = wp[WDF + i];
  for (int q = u; q < 108; q += 128) {
    int cp = q % 12, pxq = q / 12;
    int y = pxq / 3, x = pxq % 3;
    const u32* basep = SB + ((2 * y) * 7 + 2 * x) * 12 + cp;
    u32 m = 0;
    #pragma unroll
    for (int jj = 0; jj < 3; ++jj)
      #pragma unroll
      for (int kk = 0; kk < 3; ++kk) m = max2(m, basep[(jj * 7 + kk) * 12]);
    SA[cp * 9 + pxq] = m;
  }
  __syncthreads();

  // P15: dense partials: 2 img x 10 outs x 12 ci-pair chunks of 9 px
  if (t < 240) {
    int im = t / 120, r = t % 120, o = r / 12, c = r % 12;
    const u32* p3 = smem + im * AR;
    const u32* wrow = WS + o * 108 + c * 9;
    float acc = 0.f;
    #pragma unroll
    for (int s = 0; s < 9; ++s) acc = dot2(p3[c * 9 + s], wrow[s], acc);
    ((float*)(smem + im * AR))[128 + o * 12 + c] = acc;
  }
  __syncthreads();
  if (t < 20) {
    int im = t / 10, o = t % 10;
    const float* par = (const float*)(smem + im * AR) + 128 + o * 12;
    float s = 0.f;
    #pragma unroll
    for (int c = 0; c < 12; ++c) s += par[c];
    out[((long long)blockIdx.x * 2 + im) * 10 + o] = s;
  }
}

extern "C" void kernel_launch(void* const* d_in, const int* in_sizes, int n_in,
                              void* d_out, int out_size, void* d_ws, size_t ws_size,
                              hipStream_t stream) {
  const float* in = (const float*)d_in[0];
  const float* w1 = (const float*)d_in[1];
  const float* w2 = (const float*)d_in[2];
  const float* w3 = (const float*)d_in[3];
  const float* w4 = (const float*)d_in[4];
  const float* w5 = (const float*)d_in[5];
  const float* wd = (const float*)d_in[6];
  u32* wp = (u32*)d_ws;
  float* out = (float*)d_out;
  int B = in_sizes[0] / 784;

  prep_weights<<<(WTOT + 255) / 256, 256, 0, stream>>>(w1, w2, w3, w4, w5, wd, wp);
  mnist_fused<<<B / 2, 256, 0, stream>>>(in, wp, out);
}

// Round 11
// 226.605 us; speedup vs baseline: 3.4639x; 1.1446x over previous
//
#include <hip/hip_runtime.h>
#include <hip/hip_bf16.h>

typedef _Float16 half2v __attribute__((ext_vector_type(2)));
typedef _Float16 f16x8 __attribute__((ext_vector_type(8)));
typedef float f32x4 __attribute__((ext_vector_type(4)));
typedef unsigned int u32;

__device__ __forceinline__ float dot2(u32 a, u32 b, float c) {
  float d;
  asm("v_dot2_f32_f16 %0, %1, %2, %3" : "=v"(d) : "v"(a), "v"(b), "v"(c));
  return d;
}
__device__ __forceinline__ u32 pkrtz(float a, float b) {
  return __builtin_bit_cast(u32, __builtin_amdgcn_cvt_pkrtz(a, b));
}
// relu on packed f16 pair: 2 VALU (cvt_pkrtz + pk_max vs 0)
__device__ __forceinline__ u32 pack_relu(float a, float b) {
  u32 p = pkrtz(a, b);
  u32 r;
  asm("v_pk_max_f16 %0, %1, 0" : "=v"(r) : "v"(p));
  return r;
}
__device__ __forceinline__ u32 max2(u32 a, u32 b) {
  half2v x = __builtin_bit_cast(half2v, a);
  half2v y = __builtin_bit_cast(half2v, b);
  x.x = (y.x > x.x) ? y.x : x.x;
  x.y = (y.y > x.y) ? y.y : x.y;
  return __builtin_bit_cast(u32, x);
}
__device__ __forceinline__ int imin(int a, int b) { return a < b ? a : b; }

// ---- weight A-fragment layout in d_ws (u32 = f16 pair) -----------------
#define W1F 0      // conv1: 2 g. k-perm: pair p=k>>1 -> ky=p>>2, kx=(p&3)*2+(k&1)
#define W2F 512    // conv2: 4 g  (k = tap*4+ci)
#define W3F 1536   // conv3: 3 g  (k = tap*8+ci)
#define W4F 2304   // conv4: 5 g  (k = tap*16+ci)
#define W5F 3584   // conv5: 2 cot x 5 g
#define WDF 6144   // dense: [10][12cp][9px] pairs
#define WTOT 7224

__global__ void __launch_bounds__(256) prep_weights(
    const float* __restrict__ w1, const float* __restrict__ w2,
    const float* __restrict__ w3, const float* __restrict__ w4,
    const float* __restrict__ w5, const float* __restrict__ wd,
    u32* __restrict__ wp) {
  int i = threadIdx.x + blockIdx.x * 256;
  if (i < 512) {  // conv1 A-frags: w1 [3co][7][7]
    int g = i >> 8, rem = i & 255, l = rem >> 2, r = rem & 3;
    int s = l >> 4, co = l & 15;
    float v[2];
    #pragma unroll
    for (int e = 0; e < 2; ++e) {
      int k = g * 32 + 8 * s + 2 * r + e;
      int p = k >> 1;
      int ky = p >> 2, kx = ((p & 3) << 1) + (k & 1);
      v[e] = (co < 3 && ky < 7 && kx < 7) ? w1[co * 49 + ky * 7 + kx] : 0.0f;
    }
    wp[W1F + i] = pkrtz(v[0], v[1]);
  } else if (i < 1536) {  // conv2: w2 [8co][3ci][5][5]
    int q = i - W2F;
    int g = q >> 8, rem = q & 255, l = rem >> 2, r = rem & 3;
    int s = l >> 4, co = l & 15;
    float v[2];
    #pragma unroll
    for (int e = 0; e < 2; ++e) {
      int k = g * 32 + 8 * s + 2 * r + e;
      int t = k >> 2, ci = k & 3;
      v[e] = (co < 8 && ci < 3 && t < 25) ? w2[co * 75 + ci * 25 + t] : 0.0f;
    }
    wp[W2F + q] = pkrtz(v[0], v[1]);
  } else if (i < 2304) {  // conv3: w3 [10co][8ci][3][3]
    int q = i - W3F;
    int g = q >> 8, rem = q & 255, l = rem >> 2, r = rem & 3;
    int s = l >> 4, co = l & 15;
    float v[2];
    #pragma unroll
    for (int e = 0; e < 2; ++e) {
      int k = g * 32 + 8 * s + 2 * r + e;
      int t = k >> 3, ci = k & 7;
      v[e] = (co < 10 && t < 9) ? w3[co * 72 + ci * 9 + t] : 0.0f;
    }
    wp[W3F + q] = pkrtz(v[0], v[1]);
  } else if (i < 3584) {  // conv4: w4 [16co][10ci][3][3]
    int q = i - W4F;
    int g = q >> 8, rem = q & 255, l = rem >> 2, r = rem & 3;
    int s = l >> 4, co = l & 15;
    float v[2];
    #pragma unroll
    for (int e = 0; e < 2; ++e) {
      int k = g * 32 + 8 * s + 2 * r + e;
      int t = k >> 4, ci = k & 15;
      v[e] = (ci < 10 && t < 9) ? w4[co * 90 + ci * 9 + t] : 0.0f;
    }
    wp[W4F + q] = pkrtz(v[0], v[1]);
  } else if (i < 6144) {  // conv5: w5 [24co][16ci][3][3], 2 co-tiles
    int q = i - W5F;
    int cot = q / 1280, q2 = q % 1280;
    int g = q2 >> 8, rem = q2 & 255, l = rem >> 2, r = rem & 3;
    int s = l >> 4, co = cot * 16 + (l & 15);
    float v[2];
    #pragma unroll
    for (int e = 0; e < 2; ++e) {
      int k = g * 32 + 8 * s + 2 * r + e;
      int t = k >> 4, ci = k & 15;
      v[e] = (co < 24 && t < 9) ? w5[co * 144 + ci * 9 + t] : 0.0f;
    }
    wp[W5F + q] = pkrtz(v[0], v[1]);
  } else if (i < WTOT) {  // dense: wd [10][216], k = ci*9 + px
    int j = i - WDF;
    int o = j / 108, r = j % 108, cp = r / 9, s = r % 9;
    wp[WDF + j] = pkrtz(wd[o * 216 + (2 * cp) * 9 + s],
                        wd[o * 216 + (2 * cp + 1) * 9 + s]);
  }
}

// ---- fused network: 2 images per 512-thread block (8 waves) ------------
// Channels-last f16 activations (u32 = ci-pair). Per image:
//  Arena A (3600): IN dual-parity f16 [2][35][20](1400) -> a2[30][30][8ci](3600)
//    -> a3[16][16][16ci](2048) -> p2[9][9][16ci](648) -> p3(108)+partials
//  Arena B (2048): a1[32][32][4ci](2048) -> p1[16][16][8ci](1024)
//    -> a4[16][16][16ci](2048) -> a5[7][7][24ci](588)
// 49.5KB LDS -> 3 blocks/CU x 8 waves = 24 waves/CU (vs 12 with 256-thr).
#define AR_A 3600
#define AR_B 2048
#define AR (AR_A + AR_B)
#define WSOFF (2 * AR)
#define SMEMN (2 * AR + 1080)  // 12376 u32 = 49504 B

__device__ __forceinline__ f32x4 mfma16(uint4 a, uint4 b, f32x4 c) {
  return __builtin_amdgcn_mfma_f32_16x16x32_f16(
      __builtin_bit_cast(f16x8, a), __builtin_bit_cast(f16x8, b), c, 0, 0, 0);
}

__global__ void __launch_bounds__(512) mnist_fused(
    const float* __restrict__ in, const u32* __restrict__ wp,
    float* __restrict__ out) {
  __shared__ __align__(16) u32 smem[SMEMN];
  const int t = threadIdx.x;
  const int u = t & 255;        // unit within image (256 threads/img)
  const int img = t >> 8;
  const int lane = t & 63;
  const int wid = t >> 6;       // 0..7
  const long long b = (long long)blockIdx.x * 2 + img;
  u32* SA = smem + img * AR;
  u32* SB = SA + AR_A;
  u32* WS = smem + WSOFF;

  // per-lane mfma identities (col n -> (pixel-group, image))
  const int s_ = lane >> 4, n_ = lane & 15;
  const int nimg = n_ & 1, pxg = n_ >> 1;
  u32* NA = smem + nimg * AR;
  u32* NB = NA + AR_A;

  // P0: zero IN (both parities + pad rows) + a1
  {
    uint4 z = {0, 0, 0, 0};
    uint4* za = (uint4*)SA;
    uint4* zb = (uint4*)SB;
    for (int i = u; i < 350; i += 256) za[i] = z;
    for (int i = u; i < 512; i += 256) zb[i] = z;
  }
  __syncthreads();

  // P1: stage input as f16, dual parity. H0[sy*40+sx]=v, H1[sy*40+sx-1]=v
  {
    const float* inb = in + b * 784;
    _Float16* H0 = (_Float16*)SA;
    _Float16* H1 = (_Float16*)(SA + 700);
    for (int p = u; p < 784; p += 256) {
      int y = p / 28, x = p % 28;
      _Float16 h = (_Float16)inb[p];
      int sy = y + 3, sx = x + 3;
      H0[sy * 40 + sx] = h;
      H1[sy * 40 + sx - 1] = h;
    }
  }
  __syncthreads();

  // P2: conv1 MFMA, double-tile (16 px/j). y=j>>1, x=(j&1)*16+pxg
  {
    uint4 af[2];
    const uint4* wq = (const uint4*)(wp + W1F);
    af[0] = wq[lane];
    af[1] = wq[64 + lane];
    #pragma unroll 1
    for (int j = wid; j < 56; j += 8) {
      int y = j >> 1;
      int x = ((j & 1) << 4) + pxg;
      const u32* base = NA + ((x & 1) ? 700 : 0) + (x >> 1);
      f32x4 acc0 = {0.f, 0.f, 0.f, 0.f};
      f32x4 acc1 = {0.f, 0.f, 0.f, 0.f};
      #pragma unroll
      for (int g = 0; g < 2; ++g) {
        const u32* rp = base + (y + 4 * g + s_) * 20;
        uint4 b0 = {rp[0], rp[1], rp[2], rp[3]};
        uint4 b1 = {rp[4], rp[5], rp[6], rp[7]};
        acc0 = mfma16(af[g], b0, acc0);
        acc1 = mfma16(af[g], b1, acc1);
      }
      if (s_ == 0) {
        int ob = ((y + 2) * 32 + (x + 2)) * 2;
        NB[ob] = pack_relu(acc0[0], acc0[1]);
        NB[ob + 1] = pack_relu(acc0[2], acc0[3]);
        if (x + 8 < 28) {
          NB[ob + 16] = pack_relu(acc1[0], acc1[1]);
          NB[ob + 17] = pack_relu(acc1[2], acc1[3]);
        }
      }
    }
  }
  __syncthreads();

  // P3: zero a2
  {
    uint4 z = {0, 0, 0, 0};
    uint4* za = (uint4*)SA;
    for (int i = u; i < 900; i += 256) za[i] = z;
  }
  __syncthreads();

  // P4: conv2 MFMA, double-tile. K=25taps*4ci -> 4 g
  {
    uint4 af[4];
    const uint4* wq = (const uint4*)(wp + W2F);
    #pragma unroll
    for (int g = 0; g < 4; ++g) af[g] = wq[g * 64 + lane];
    int ro0[4], ro1[4];
    #pragma unroll
    for (int g = 0; g < 4; ++g) {
      int t0 = imin(g * 8 + 2 * s_, 24), t1 = imin(g * 8 + 2 * s_ + 1, 24);
      ro0[g] = ((t0 / 5) * 32 + t0 % 5) * 2;
      ro1[g] = ((t1 / 5) * 32 + t1 % 5) * 2;
    }
    #pragma unroll 1
    for (int j = wid; j < 56; j += 8) {
      int y = j >> 1;
      int x = ((j & 1) << 4) + pxg;
      int ab = (y * 32 + x) * 2;
      f32x4 acc0 = {0.f, 0.f, 0.f, 0.f};
      f32x4 acc1 = {0.f, 0.f, 0.f, 0.f};
      #pragma unroll
      for (int g = 0; g < 4; ++g) {
        uint2 lo0 = *(const uint2*)(NB + ab + ro0[g]);
        uint2 hi0 = *(const uint2*)(NB + ab + ro1[g]);
        uint4 b0 = {lo0.x, lo0.y, hi0.x, hi0.y};
        acc0 = mfma16(af[g], b0, acc0);
        uint2 lo1 = *(const uint2*)(NB + ab + 16 + ro0[g]);
        uint2 hi1 = *(const uint2*)(NB + ab + 16 + ro1[g]);
        uint4 b1 = {lo1.x, lo1.y, hi1.x, hi1.y};
        acc1 = mfma16(af[g], b1, acc1);
      }
      if (s_ < 2) {
        int ob = ((y + 1) * 30 + (x + 1)) * 4;
        NA[ob + 2 * s_] = pack_relu(acc0[0], acc0[1]);
        NA[ob + 2 * s_ + 1] = pack_relu(acc0[2], acc0[3]);
        if (x + 8 < 28) {
          NA[ob + 32 + 2 * s_] = pack_relu(acc1[0], acc1[1]);
          NA[ob + 32 + 2 * s_ + 1] = pack_relu(acc1[2], acc1[3]);
        }
      }
    }
  }
  __syncthreads();

  // P5: zero p1
  {
    uint4 z = {0, 0, 0, 0};
    uint4* zb = (uint4*)SB;
    for (int i = u; i < 256; i += 256) zb[i] = z;
  }
  __syncthreads();

  // P6: pool1 3x3 s2 p1: a2[30][30][4] -> p1[16][16][4], uint2 lanes
  for (int q = u; q < 392; q += 256) {
    int cpp = q & 1, pxq = q >> 1;
    int y = pxq / 14, x = pxq % 14;
    const u32* basep = SA + ((2 * y) * 30 + 2 * x) * 4 + cpp * 2;
    u32 m0 = 0, m1 = 0;
    #pragma unroll
    for (int jj = 0; jj < 3; ++jj)
      #pragma unroll
      for (int kk = 0; kk < 3; ++kk) {
        uint2 v = *(const uint2*)(basep + (jj * 30 + kk) * 4);
        m0 = max2(m0, v.x);
        m1 = max2(m1, v.y);
      }
    uint2 r = {m0, m1};
    *(uint2*)(SB + ((y + 1) * 16 + (x + 1)) * 4 + cpp * 2) = r;
  }
  __syncthreads();

  // P7: zero a3
  {
    uint4 z = {0, 0, 0, 0};
    uint4* za = (uint4*)SA;
    for (int i = u; i < 512; i += 256) za[i] = z;
  }
  __syncthreads();

  // P8: conv3 MFMA. no-div tiles: y=j>>1, x=(j&1)*8+pxg, mask x<14
  {
    uint4 af[3];
    const uint4* wq = (const uint4*)(wp + W3F);
    #pragma unroll
    for (int g = 0; g < 3; ++g) af[g] = wq[g * 64 + lane];
    int roff[3];
    #pragma unroll
    for (int g = 0; g < 3; ++g) {
      int tt = imin(g * 4 + s_, 8);
      roff[g] = ((tt / 3) * 16 + tt % 3) * 4;
    }
    #pragma unroll 1
    for (int j = wid; j < 28; j += 8) {
      int y = j >> 1;
      int x = ((j & 1) << 3) + pxg;
      int ab = (y * 16 + x) * 4;
      f32x4 acc = {0.f, 0.f, 0.f, 0.f};
      #pragma unroll
      for (int g = 0; g < 3; ++g) {
        uint4 bv = *(const uint4*)(NB + ab + roff[g]);
        acc = mfma16(af[g], bv, acc);
      }
      if (x < 14) {
        int ob = ((y + 1) * 16 + (x + 1)) * 8;
        int cp0 = 2 * s_, cp1 = 2 * s_ + 1;
        u32 p0 = pack_relu(acc[0], acc[1]);
        u32 p1v = pack_relu(acc[2], acc[3]);
        if (cp0 < 5) NA[ob + cp0] = p0;
        if (cp1 < 5) NA[ob + cp1] = p1v;
      }
    }
  }
  __syncthreads();

  // P9: zero a4
  {
    uint4 z = {0, 0, 0, 0};
    uint4* zb = (uint4*)SB;
    for (int i = u; i < 512; i += 256) zb[i] = z;
  }
  __syncthreads();

  // P10: conv4 MFMA. no-div tiles
  {
    uint4 af[5];
    const uint4* wq = (const uint4*)(wp + W4F);
    #pragma unroll
    for (int g = 0; g < 5; ++g) af[g] = wq[g * 64 + lane];
    int roff[5];
    #pragma unroll
    for (int g = 0; g < 5; ++g) {
      int tt = imin(g * 2 + (s_ >> 1), 8);
      roff[g] = ((tt / 3) * 16 + tt % 3) * 8 + (s_ & 1) * 4;
    }
    #pragma unroll 1
    for (int j = wid; j < 28; j += 8) {
      int y = j >> 1;
      int x = ((j & 1) << 3) + pxg;
      int ab = (y * 16 + x) * 8;
      f32x4 acc = {0.f, 0.f, 0.f, 0.f};
      #pragma unroll
      for (int g = 0; g < 5; ++g) {
        uint4 bv = *(const uint4*)(NA + ab + roff[g]);
        acc = mfma16(af[g], bv, acc);
      }
      if (x < 14) {
        int ob = ((y + 1) * 16 + (x + 1)) * 8;
        NB[ob + 2 * s_] = pack_relu(acc[0], acc[1]);
        NB[ob + 2 * s_ + 1] = pack_relu(acc[2], acc[3]);
      }
    }
  }
  __syncthreads();

  // P11: zero p2
  {
    uint4 z = {0, 0, 0, 0};
    uint4* za = (uint4*)SA;
    for (int i = u; i < 162; i += 256) za[i] = z;
  }
  __syncthreads();

  // P12: pool2 3x3 s2 p1: a4[16][16][8] -> p2[9][9][8], uint4 lanes
  if (u < 98) {
    int cpq = u & 1, pxq = u >> 1;
    int y = pxq / 7, x = pxq % 7;
    const u32* basep = SB + ((2 * y) * 16 + 2 * x) * 8 + cpq * 4;
    u32 m0 = 0, m1 = 0, m2 = 0, m3 = 0;
    #pragma unroll
    for (int jj = 0; jj < 3; ++jj)
      #pragma unroll
      for (int kk = 0; kk < 3; ++kk) {
        uint4 v = *(const uint4*)(basep + (jj * 16 + kk) * 8);
        m0 = max2(m0, v.x);
        m1 = max2(m1, v.y);
        m2 = max2(m2, v.z);
        m3 = max2(m3, v.w);
      }
    uint4 r = {m0, m1, m2, m3};
    *(uint4*)(SA + ((y + 1) * 9 + (x + 1)) * 8 + cpq * 4) = r;
  }
  __syncthreads();

  // P13: conv5 MFMA. no-div: cot=(j>6), y=pj, x=pxg, mask x<7
  {
    int roff[5];
    #pragma unroll
    for (int g = 0; g < 5; ++g) {
      int tt = imin(g * 2 + (s_ >> 1), 8);
      roff[g] = ((tt / 3) * 9 + tt % 3) * 8 + (s_ & 1) * 4;
    }
    #pragma unroll 1
    for (int j = wid; j < 14; j += 8) {
      int cot = j > 6 ? 1 : 0;
      int y = j - (cot ? 7 : 0);
      int x = pxg;
      uint4 af[5];
      const uint4* wq = (const uint4*)(wp + W5F + cot * 1280);
      #pragma unroll
      for (int g = 0; g < 5; ++g) af[g] = wq[g * 64 + lane];
      int ab = (y * 9 + x) * 8;
      f32x4 acc = {0.f, 0.f, 0.f, 0.f};
      #pragma unroll
      for (int g = 0; g < 5; ++g) {
        uint4 bv = *(const uint4*)(NA + ab + roff[g]);
        acc = mfma16(af[g], bv, acc);
      }
      if (x < 7 && (cot == 0 || s_ < 2)) {
        int ob = (y * 7 + x) * 12 + cot * 8;
        NB[ob + 2 * s_] = pack_relu(acc[0], acc[1]);
        NB[ob + 2 * s_ + 1] = pack_relu(acc[2], acc[3]);
      }
    }
  }
  __syncthreads();

  // P14: stage wd; pool3 3x3 s2 p0: a5[7][7][12] -> p3 planar [12cp][9]
  for (int i = t; i < 1080; i += 512) WS[i] = wp[WDF + i];
  for (int q = u; q < 108; q += 256) {
    int cp = q % 12, pxq = q / 12;
    int y = pxq / 3, x = pxq % 3;
    const u32* basep = SB + ((2 * y) * 7 + 2 * x) * 12 + cp;
    u32 m = 0;
    #pragma unroll
    for (int jj = 0; jj < 3; ++jj)
      #pragma unroll
      for (int kk = 0; kk < 3; ++kk) m = max2(m, basep[(jj * 7 + kk) * 12]);
    SA[cp * 9 + pxq] = m;
  }
  __syncthreads();

  // P15: dense partials: 2 img x 10 outs x 12 ci-pair chunks of 9 px
  if (t < 240) {
    int im = t / 120, r = t % 120, o = r / 12, c = r % 12;
    const u32* p3 = smem + im * AR;
    const u32* wrow = WS + o * 108 + c * 9;
    float acc = 0.f;
    #pragma unroll
    for (int s = 0; s < 9; ++s) acc = dot2(p3[c * 9 + s], wrow[s], acc);
    ((float*)(smem + im * AR))[128 + o * 12 + c] = acc;
  }
  __syncthreads();
  if (t < 20) {
    int im = t / 10, o = t % 10;
    const float* par = (const float*)(smem + im * AR) + 128 + o * 12;
    float s = 0.f;
    #pragma unroll
    for (int c = 0; c < 12; ++c) s += par[c];
    out[((long long)blockIdx.x * 2 + im) * 10 + o] = s;
  }
}

extern "C" void kernel_launch(void* const* d_in, const int* in_sizes, int n_in,
                              void* d_out, int out_size, void* d_ws, size_t ws_size,
                              hipStream_t stream) {
  const float* in = (const float*)d_in[0];
  const float* w1 = (const float*)d_in[1];
  const float* w2 = (const float*)d_in[2];
  const float* w3 = (const float*)d_in[3];
  const float* w4 = (const float*)d_in[4];
  const float* w5 = (const float*)d_in[5];
  const float* wd = (const float*)d_in[6];
  u32* wp = (u32*)d_ws;
  float* out = (float*)d_out;
  int B = in_sizes[0] / 784;

  prep_weights<<<(WTOT + 255) / 256, 256, 0, stream>>>(w1, w2, w3, w4, w5, wd, wp);
  mnist_fused<<<B / 2, 512, 0, stream>>>(in, wp, out);
}

// Round 15
// 194.782 us; speedup vs baseline: 4.0299x; 1.1634x over previous
//
#include <hip/hip_runtime.h>
#include <hip/hip_bf16.h>

typedef _Float16 half2v __attribute__((ext_vector_type(2)));
typedef _Float16 f16x8 __attribute__((ext_vector_type(8)));
typedef float f32x4 __attribute__((ext_vector_type(4)));
typedef unsigned int u32;

__device__ __forceinline__ float dot2(u32 a, u32 b, float c) {
  float d;
  asm("v_dot2_f32_f16 %0, %1, %2, %3" : "=v"(d) : "v"(a), "v"(b), "v"(c));
  return d;
}
__device__ __forceinline__ u32 pkrtz(float a, float b) {
  return __builtin_bit_cast(u32, __builtin_amdgcn_cvt_pkrtz(a, b));
}
__device__ __forceinline__ u32 pack_relu(float a, float b) {
  u32 p = pkrtz(a, b);
  u32 r;
  asm("v_pk_max_f16 %0, %1, 0" : "=v"(r) : "v"(p));
  return r;
}
__device__ __forceinline__ u32 max2(u32 a, u32 b) {
  half2v x = __builtin_bit_cast(half2v, a);
  half2v y = __builtin_bit_cast(half2v, b);
  x.x = (y.x > x.x) ? y.x : x.x;
  x.y = (y.y > x.y) ? y.y : x.y;
  return __builtin_bit_cast(u32, x);
}
__device__ __forceinline__ int imin(int a, int b) { return a < b ? a : b; }

// ---- weight A-fragment layout in d_ws (u32 = f16 pair) -----------------
#define W1F 0      // conv1: 2 g. k-perm: pair p=k>>1 -> ky=p>>2, kx=(p&3)*2+(k&1)
#define W2F 512    // conv2: 4 g  (k = tap*4+ci)
#define W3F 1536   // conv3: 3 g  (k = tap*8+ci)
#define W4F 2304   // conv4: 5 g  (k = tap*16+ci)
#define W5F 3584   // conv5: 2 cot x 5 g
#define WDF 6144   // dense: [10][12cp][9px] pairs
#define WTOT 7224

__global__ void __launch_bounds__(256) prep_weights(
    const float* __restrict__ w1, const float* __restrict__ w2,
    const float* __restrict__ w3, const float* __restrict__ w4,
    const float* __restrict__ w5, const float* __restrict__ wd,
    u32* __restrict__ wp) {
  int i = threadIdx.x + blockIdx.x * 256;
  if (i < 512) {  // conv1 A-frags: w1 [3co][7][7]
    int g = i >> 8, rem = i & 255, l = rem >> 2, r = rem & 3;
    int s = l >> 4, co = l & 15;
    float v[2];
    #pragma unroll
    for (int e = 0; e < 2; ++e) {
      int k = g * 32 + 8 * s + 2 * r + e;
      int p = k >> 1;
      int ky = p >> 2, kx = ((p & 3) << 1) + (k & 1);
      v[e] = (co < 3 && ky < 7 && kx < 7) ? w1[co * 49 + ky * 7 + kx] : 0.0f;
    }
    wp[W1F + i] = pkrtz(v[0], v[1]);
  } else if (i < 1536) {  // conv2: w2 [8co][3ci][5][5]
    int q = i - W2F;
    int g = q >> 8, rem = q & 255, l = rem >> 2, r = rem & 3;
    int s = l >> 4, co = l & 15;
    float v[2];
    #pragma unroll
    for (int e = 0; e < 2; ++e) {
      int k = g * 32 + 8 * s + 2 * r + e;
      int t = k >> 2, ci = k & 3;
      v[e] = (co < 8 && ci < 3 && t < 25) ? w2[co * 75 + ci * 25 + t] : 0.0f;
    }
    wp[W2F + q] = pkrtz(v[0], v[1]);
  } else if (i < 2304) {  // conv3: w3 [10co][8ci][3][3]
    int q = i - W3F;
    int g = q >> 8, rem = q & 255, l = rem >> 2, r = rem & 3;
    int s = l >> 4, co = l & 15;
    float v[2];
    #pragma unroll
    for (int e = 0; e < 2; ++e) {
      int k = g * 32 + 8 * s + 2 * r + e;
      int t = k >> 3, ci = k & 7;
      v[e] = (co < 10 && t < 9) ? w3[co * 72 + ci * 9 + t] : 0.0f;
    }
    wp[W3F + q] = pkrtz(v[0], v[1]);
  } else if (i < 3584) {  // conv4: w4 [16co][10ci][3][3]
    int q = i - W4F;
    int g = q >> 8, rem = q & 255, l = rem >> 2, r = rem & 3;
    int s = l >> 4, co = l & 15;
    float v[2];
    #pragma unroll
    for (int e = 0; e < 2; ++e) {
      int k = g * 32 + 8 * s + 2 * r + e;
      int t = k >> 4, ci = k & 15;
      v[e] = (ci < 10 && t < 9) ? w4[co * 90 + ci * 9 + t] : 0.0f;
    }
    wp[W4F + q] = pkrtz(v[0], v[1]);
  } else if (i < 6144) {  // conv5: w5 [24co][16ci][3][3], 2 co-tiles
    int q = i - W5F;
    int cot = q / 1280, q2 = q % 1280;
    int g = q2 >> 8, rem = q2 & 255, l = rem >> 2, r = rem & 3;
    int s = l >> 4, co = cot * 16 + (l & 15);
    float v[2];
    #pragma unroll
    for (int e = 0; e < 2; ++e) {
      int k = g * 32 + 8 * s + 2 * r + e;
      int t = k >> 4, ci = k & 15;
      v[e] = (co < 24 && t < 9) ? w5[co * 144 + ci * 9 + t] : 0.0f;
    }
    wp[W5F + q] = pkrtz(v[0], v[1]);
  } else if (i < WTOT) {  // dense: wd [10][216], k = ci*9 + px
    int j = i - WDF;
    int o = j / 108, r = j % 108, cp = r / 9, s = r % 9;
    wp[WDF + j] = pkrtz(wd[o * 216 + (2 * cp) * 9 + s],
                        wd[o * 216 + (2 * cp + 1) * 9 + s]);
  }
}

// ---- fused network: 1 image per 256-thread block -----------------------
// Channels-last f16 activations (u32 = ci-pair). Per image:
//  Arena A (3600): IN dual-parity f16 [2][35][20](1400) -> a2[30][30][8ci](3600)
//    -> a3[16][16][16ci](2048) -> p2[9][9][16ci](648) -> p3(108)+partials
//  Arena B (2048): a1[32][32][4ci](2048) -> p1[16][16][8ci](1024)
//    -> a4[16][16][16ci](2048) -> a5[7][7][24ci](588)
// 22.6KB LDS -> 7 blocks/CU x 4 waves = 28 waves/CU.
#define AR_A 3600
#define AR_B 2048
#define SMEMN (AR_A + AR_B)  // 5648 u32 = 22592 B

__device__ __forceinline__ f32x4 mfma16(uint4 a, uint4 b, f32x4 c) {
  return __builtin_amdgcn_mfma_f32_16x16x32_f16(
      __builtin_bit_cast(f16x8, a), __builtin_bit_cast(f16x8, b), c, 0, 0, 0);
}

__global__ void __launch_bounds__(256) mnist_fused(
    const float* __restrict__ in, const u32* __restrict__ wp,
    float* __restrict__ out) {
  __shared__ __align__(16) u32 smem[SMEMN];
  const int t = threadIdx.x;
  const int lane = t & 63;
  const int wid = t >> 6;  // 0..3
  const long long b = blockIdx.x;
  u32* SA = smem;
  u32* SB = smem + AR_A;

  // per-lane mfma identities: col n = pixel within 16-px tile
  const int s_ = lane >> 4, pxg = lane & 15;

  // P0: zero IN (both parities) + a1
  {
    uint4 z = {0, 0, 0, 0};
    uint4* za = (uint4*)SA;
    uint4* zb = (uint4*)SB;
    for (int i = t; i < 350; i += 256) za[i] = z;
    for (int i = t; i < 512; i += 256) zb[i] = z;
  }
  __syncthreads();

  // P1: stage input as f16, dual parity. H0[sy*40+sx]=v, H1[sy*40+sx-1]=v
  {
    const float* inb = in + b * 784;
    _Float16* H0 = (_Float16*)SA;
    _Float16* H1 = (_Float16*)(SA + 700);
    for (int p = t; p < 784; p += 256) {
      int y = p / 28, x = p % 28;
      _Float16 h = (_Float16)inb[p];
      int sy = y + 3, sx = x + 3;
      H0[sy * 40 + sx] = h;
      H1[sy * 40 + sx - 1] = h;
    }
  }
  __syncthreads();

  // P2: conv1 MFMA. 16-px tiles: y=j>>1, x=(j&1)*16+pxg, mask x<28
  {
    uint4 af[2];
    const uint4* wq = (const uint4*)(wp + W1F);
    af[0] = wq[lane];
    af[1] = wq[64 + lane];
    #pragma unroll 1
    for (int j = wid; j < 56; j += 4) {
      int y = j >> 1;
      int x = ((j & 1) << 4) + pxg;
      const u32* base = SA + ((x & 1) ? 700 : 0) + (x >> 1);
      f32x4 acc = {0.f, 0.f, 0.f, 0.f};
      #pragma unroll
      for (int g = 0; g < 2; ++g) {
        const u32* rp = base + (y + 4 * g + s_) * 20;
        uint4 bv = {rp[0], rp[1], rp[2], rp[3]};
        acc = mfma16(af[g], bv, acc);
      }
      if (s_ == 0 && x < 28) {
        int ob = ((y + 2) * 32 + (x + 2)) * 2;
        SB[ob] = pack_relu(acc[0], acc[1]);
        SB[ob + 1] = pack_relu(acc[2], acc[3]);
      }
    }
  }
  __syncthreads();

  // P3: zero a2
  {
    uint4 z = {0, 0, 0, 0};
    uint4* za = (uint4*)SA;
    for (int i = t; i < 900; i += 256) za[i] = z;
  }
  __syncthreads();

  // P4: conv2 MFMA. K=25taps*4ci -> 4 g
  {
    uint4 af[4];
    const uint4* wq = (const uint4*)(wp + W2F);
    #pragma unroll
    for (int g = 0; g < 4; ++g) af[g] = wq[g * 64 + lane];
    int ro0[4], ro1[4];
    #pragma unroll
    for (int g = 0; g < 4; ++g) {
      int t0 = imin(g * 8 + 2 * s_, 24), t1 = imin(g * 8 + 2 * s_ + 1, 24);
      ro0[g] = ((t0 / 5) * 32 + t0 % 5) * 2;
      ro1[g] = ((t1 / 5) * 32 + t1 % 5) * 2;
    }
    #pragma unroll 1
    for (int j = wid; j < 56; j += 4) {
      int y = j >> 1;
      int x = ((j & 1) << 4) + pxg;
      int ab = (y * 32 + x) * 2;
      f32x4 acc = {0.f, 0.f, 0.f, 0.f};
      #pragma unroll
      for (int g = 0; g < 4; ++g) {
        uint2 lo = *(const uint2*)(SB + ab + ro0[g]);
        uint2 hi = *(const uint2*)(SB + ab + ro1[g]);
        uint4 bv = {lo.x, lo.y, hi.x, hi.y};
        acc = mfma16(af[g], bv, acc);
      }
      if (s_ < 2 && x < 28) {
        int ob = ((y + 1) * 30 + (x + 1)) * 4;
        SA[ob + 2 * s_] = pack_relu(acc[0], acc[1]);
        SA[ob + 2 * s_ + 1] = pack_relu(acc[2], acc[3]);
      }
    }
  }
  __syncthreads();

  // P5: zero p1
  {
    uint4 z = {0, 0, 0, 0};
    uint4* zb = (uint4*)SB;
    for (int i = t; i < 256; i += 256) zb[i] = z;
  }
  __syncthreads();

  // P6: pool1 3x3 s2 p1: a2[30][30][4] -> p1[16][16][4], uint2 lanes
  for (int q = t; q < 392; q += 256) {
    int cpp = q & 1, pxq = q >> 1;
    int y = pxq / 14, x = pxq % 14;
    const u32* basep = SA + ((2 * y) * 30 + 2 * x) * 4 + cpp * 2;
    u32 m0 = 0, m1 = 0;
    #pragma unroll
    for (int jj = 0; jj < 3; ++jj)
      #pragma unroll
      for (int kk = 0; kk < 3; ++kk) {
        uint2 v = *(const uint2*)(basep + (jj * 30 + kk) * 4);
        m0 = max2(m0, v.x);
        m1 = max2(m1, v.y);
      }
    uint2 r = {m0, m1};
    *(uint2*)(SB + ((y + 1) * 16 + (x + 1)) * 4 + cpp * 2) = r;
  }
  __syncthreads();

  // P7: zero a3
  {
    uint4 z = {0, 0, 0, 0};
    uint4* za = (uint4*)SA;
    for (int i = t; i < 512; i += 256) za[i] = z;
  }
  __syncthreads();

  // P8: conv3 MFMA. tiles: y=j (14 rows), x=pxg, mask x<14
  {
    uint4 af[3];
    const uint4* wq = (const uint4*)(wp + W3F);
    #pragma unroll
    for (int g = 0; g < 3; ++g) af[g] = wq[g * 64 + lane];
    int roff[3];
    #pragma unroll
    for (int g = 0; g < 3; ++g) {
      int tt = imin(g * 4 + s_, 8);
      roff[g] = ((tt / 3) * 16 + tt % 3) * 4;
    }
    #pragma unroll 1
    for (int j = wid; j < 14; j += 4) {
      int y = j;
      int x = pxg;
      int ab = (y * 16 + x) * 4;
      f32x4 acc = {0.f, 0.f, 0.f, 0.f};
      #pragma unroll
      for (int g = 0; g < 3; ++g) {
        uint4 bv = *(const uint4*)(SB + ab + roff[g]);
        acc = mfma16(af[g], bv, acc);
      }
      if (x < 14) {
        int ob = ((y + 1) * 16 + (x + 1)) * 8;
        int cp0 = 2 * s_, cp1 = 2 * s_ + 1;
        u32 p0 = pack_relu(acc[0], acc[1]);
        u32 p1v = pack_relu(acc[2], acc[3]);
        if (cp0 < 5) SA[ob + cp0] = p0;
        if (cp1 < 5) SA[ob + cp1] = p1v;
      }
    }
  }
  __syncthreads();

  // P9: zero a4
  {
    uint4 z = {0, 0, 0, 0};
    uint4* zb = (uint4*)SB;
    for (int i = t; i < 512; i += 256) zb[i] = z;
  }
  __syncthreads();

  // P10: conv4 MFMA. tiles: y=j, x=pxg, mask x<14
  {
    uint4 af[5];
    const uint4* wq = (const uint4*)(wp + W4F);
    #pragma unroll
    for (int g = 0; g < 5; ++g) af[g] = wq[g * 64 + lane];
    int roff[5];
    #pragma unroll
    for (int g = 0; g < 5; ++g) {
      int tt = imin(g * 2 + (s_ >> 1), 8);
      roff[g] = ((tt / 3) * 16 + tt % 3) * 8 + (s_ & 1) * 4;
    }
    #pragma unroll 1
    for (int j = wid; j < 14; j += 4) {
      int y = j;
      int x = pxg;
      int ab = (y * 16 + x) * 8;
      f32x4 acc = {0.f, 0.f, 0.f, 0.f};
      #pragma unroll
      for (int g = 0; g < 5; ++g) {
        uint4 bv = *(const uint4*)(SA + ab + roff[g]);
        acc = mfma16(af[g], bv, acc);
      }
      if (x < 14) {
        int ob = ((y + 1) * 16 + (x + 1)) * 8;
        SB[ob + 2 * s_] = pack_relu(acc[0], acc[1]);
        SB[ob + 2 * s_ + 1] = pack_relu(acc[2], acc[3]);
      }
    }
  }
  __syncthreads();

  // P11: zero p2
  {
    uint4 z = {0, 0, 0, 0};
    uint4* za = (uint4*)SA;
    for (int i = t; i < 162; i += 256) za[i] = z;
  }
  __syncthreads();

  // P12: pool2 3x3 s2 p1: a4[16][16][8] -> p2[9][9][8], uint4 lanes
  if (t < 98) {
    int cpq = t & 1, pxq = t >> 1;
    int y = pxq / 7, x = pxq % 7;
    const u32* basep = SB + ((2 * y) * 16 + 2 * x) * 8 + cpq * 4;
    u32 m0 = 0, m1 = 0, m2 = 0, m3 = 0;
    #pragma unroll
    for (int jj = 0; jj < 3; ++jj)
      #pragma unroll
      for (int kk = 0; kk < 3; ++kk) {
        uint4 v = *(const uint4*)(basep + (jj * 16 + kk) * 8);
        m0 = max2(m0, v.x);
        m1 = max2(m1, v.y);
        m2 = max2(m2, v.z);
        m3 = max2(m3, v.w);
      }
    uint4 r = {m0, m1, m2, m3};
    *(uint4*)(SA + ((y + 1) * 9 + (x + 1)) * 8 + cpq * 4) = r;
  }
  __syncthreads();

  // P13: conv5 MFMA. units: (7 rows x 2 cot), y=row, x=pxg, mask x<7
  {
    int roff[5];
    #pragma unroll
    for (int g = 0; g < 5; ++g) {
      int tt = imin(g * 2 + (s_ >> 1), 8);
      roff[g] = ((tt / 3) * 9 + tt % 3) * 8 + (s_ & 1) * 4;
    }
    #pragma unroll 1
    for (int j = wid; j < 14; j += 4) {
      int cot = j > 6 ? 1 : 0;
      int y = j - (cot ? 7 : 0);
      int x = pxg;
      uint4 af[5];
      const uint4* wq = (const uint4*)(wp + W5F + cot * 1280);
      #pragma unroll
      for (int g = 0; g < 5; ++g) af[g] = wq[g * 64 + lane];
      int ab = (y * 9 + x) * 8;
      f32x4 acc = {0.f, 0.f, 0.f, 0.f};
      #pragma unroll
      for (int g = 0; g < 5; ++g) {
        uint4 bv = *(const uint4*)(SA + ab + roff[g]);
        acc = mfma16(af[g], bv, acc);
      }
      if (x < 7 && (cot == 0 || s_ < 2)) {
        int ob = (y * 7 + x) * 12 + cot * 8;
        SB[ob + 2 * s_] = pack_relu(acc[0], acc[1]);
        SB[ob + 2 * s_ + 1] = pack_relu(acc[2], acc[3]);
      }
    }
  }
  __syncthreads();

  // P14: pool3 3x3 s2 p0: a5[7][7][12] -> p3 planar [12cp][9] at SA[0..107]
  if (t < 108) {
    int cp = t % 12, pxq = t / 12;
    int y = pxq / 3, x = pxq % 3;
    const u32* basep = SB + ((2 * y) * 7 + 2 * x) * 12 + cp;
    u32 m = 0;
    #pragma unroll
    for (int jj = 0; jj < 3; ++jj)
      #pragma unroll
      for (int kk = 0; kk < 3; ++kk) m = max2(m, basep[(jj * 7 + kk) * 12]);
    SA[cp * 9 + pxq] = m;
  }
  __syncthreads();

  // P15: dense partials: 10 outs x 12 ci-pair chunks of 9 px (wd from L2)
  if (t < 120) {
    int o = t / 12, c = t % 12;
    const u32* wrow = wp + WDF + o * 108 + c * 9;
    float acc = 0.f;
    #pragma unroll
    for (int s = 0; s < 9; ++s) acc = dot2(SA[c * 9 + s], wrow[s], acc);
    ((float*)SA)[128 + o * 12 + c] = acc;
  }
  __syncthreads();
  if (t < 10) {
    const float* par = (const float*)SA + 128 + t * 12;
    float s = 0.f;
    #pragma unroll
    for (int c = 0; c < 12; ++c) s += par[c];
    out[b * 10 + t] = s;
  }
}

extern "C" void kernel_launch(void* const* d_in, const int* in_sizes, int n_in,
                              void* d_out, int out_size, void* d_ws, size_t ws_size,
                              hipStream_t stream) {
  const float* in = (const float*)d_in[0];
  const float* w1 = (const float*)d_in[1];
  const float* w2 = (const float*)d_in[2];
  const float* w3 = (const float*)d_in[3];
  const float* w4 = (const float*)d_in[4];
  const float* w5 = (const float*)d_in[5];
  const float* wd = (const float*)d_in[6];
  u32* wp = (u32*)d_ws;
  float* out = (float*)d_out;
  int B = in_sizes[0] / 784;

  prep_weights<<<(WTOT + 255) / 256, 256, 0, stream>>>(w1, w2, w3, w4, w5, wd, wp);
  mnist_fused<<<B, 256, 0, stream>>>(in, wp, out);
}

// Round 18
// 190.411 us; speedup vs baseline: 4.1224x; 1.0230x over previous
//
#include <hip/hip_runtime.h>
#include <hip/hip_bf16.h>

typedef _Float16 half2v __attribute__((ext_vector_type(2)));
typedef _Float16 f16x8 __attribute__((ext_vector_type(8)));
typedef float f32x4 __attribute__((ext_vector_type(4)));
typedef unsigned int u32;

__device__ __forceinline__ float dot2(u32 a, u32 b, float c) {
  float d;
  asm("v_dot2_f32_f16 %0, %1, %2, %3" : "=v"(d) : "v"(a), "v"(b), "v"(c));
  return d;
}
__device__ __forceinline__ u32 pkrtz(float a, float b) {
  return __builtin_bit_cast(u32, __builtin_amdgcn_cvt_pkrtz(a, b));
}
__device__ __forceinline__ u32 pack_relu(float a, float b) {
  u32 p = pkrtz(a, b);
  u32 r;
  asm("v_pk_max_f16 %0, %1, 0" : "=v"(r) : "v"(p));
  return r;
}
__device__ __forceinline__ u32 max2(u32 a, u32 b) {
  half2v x = __builtin_bit_cast(half2v, a);
  half2v y = __builtin_bit_cast(half2v, b);
  x.x = (y.x > x.x) ? y.x : x.x;
  x.y = (y.y > x.y) ? y.y : x.y;
  return __builtin_bit_cast(u32, x);
}
__device__ __forceinline__ int imin(int a, int b) { return a < b ? a : b; }

// ---- weight A-fragment layout in d_ws (u32 = f16 pair) -----------------
#define W1F 0      // conv1: 2 g. k-perm: pair p=k>>1 -> ky=p>>2, kx=(p&3)*2+(k&1)
#define W2F 512    // conv2: 4 g  (k = tap*4+ci)
#define W3F 1536   // conv3: 3 g  (k = tap*8+ci)
#define W4F 2304   // conv4: 5 g  (k = tap*16+ci)
#define W5F 3584   // conv5: 2 cot x 5 g
#define WDF 6144   // dense: [10][12cp][9px] pairs
#define WTOT 7224

__global__ void __launch_bounds__(256) prep_weights(
    const float* __restrict__ w1, const float* __restrict__ w2,
    const float* __restrict__ w3, const float* __restrict__ w4,
    const float* __restrict__ w5, const float* __restrict__ wd,
    u32* __restrict__ wp) {
  int i = threadIdx.x + blockIdx.x * 256;
  if (i < 512) {  // conv1 A-frags: w1 [3co][7][7]
    int g = i >> 8, rem = i & 255, l = rem >> 2, r = rem & 3;
    int s = l >> 4, co = l & 15;
    float v[2];
    #pragma unroll
    for (int e = 0; e < 2; ++e) {
      int k = g * 32 + 8 * s + 2 * r + e;
      int p = k >> 1;
      int ky = p >> 2, kx = ((p & 3) << 1) + (k & 1);
      v[e] = (co < 3 && ky < 7 && kx < 7) ? w1[co * 49 + ky * 7 + kx] : 0.0f;
    }
    wp[W1F + i] = pkrtz(v[0], v[1]);
  } else if (i < 1536) {  // conv2: w2 [8co][3ci][5][5]
    int q = i - W2F;
    int g = q >> 8, rem = q & 255, l = rem >> 2, r = rem & 3;
    int s = l >> 4, co = l & 15;
    float v[2];
    #pragma unroll
    for (int e = 0; e < 2; ++e) {
      int k = g * 32 + 8 * s + 2 * r + e;
      int t = k >> 2, ci = k & 3;
      v[e] = (co < 8 && ci < 3 && t < 25) ? w2[co * 75 + ci * 25 + t] : 0.0f;
    }
    wp[W2F + q] = pkrtz(v[0], v[1]);
  } else if (i < 2304) {  // conv3: w3 [10co][8ci][3][3]
    int q = i - W3F;
    int g = q >> 8, rem = q & 255, l = rem >> 2, r = rem & 3;
    int s = l >> 4, co = l & 15;
    float v[2];
    #pragma unroll
    for (int e = 0; e < 2; ++e) {
      int k = g * 32 + 8 * s + 2 * r + e;
      int t = k >> 3, ci = k & 7;
      v[e] = (co < 10 && t < 9) ? w3[co * 72 + ci * 9 + t] : 0.0f;
    }
    wp[W3F + q] = pkrtz(v[0], v[1]);
  } else if (i < 3584) {  // conv4: w4 [16co][10ci][3][3]
    int q = i - W4F;
    int g = q >> 8, rem = q & 255, l = rem >> 2, r = rem & 3;
    int s = l >> 4, co = l & 15;
    float v[2];
    #pragma unroll
    for (int e = 0; e < 2; ++e) {
      int k = g * 32 + 8 * s + 2 * r + e;
      int t = k >> 4, ci = k & 15;
      v[e] = (ci < 10 && t < 9) ? w4[co * 90 + ci * 9 + t] : 0.0f;
    }
    wp[W4F + q] = pkrtz(v[0], v[1]);
  } else if (i < 6144) {  // conv5: w5 [24co][16ci][3][3], 2 co-tiles
    int q = i - W5F;
    int cot = q / 1280, q2 = q % 1280;
    int g = q2 >> 8, rem = q2 & 255, l = rem >> 2, r = rem & 3;
    int s = l >> 4, co = cot * 16 + (l & 15);
    float v[2];
    #pragma unroll
    for (int e = 0; e < 2; ++e) {
      int k = g * 32 + 8 * s + 2 * r + e;
      int t = k >> 4, ci = k & 15;
      v[e] = (co < 24 && t < 9) ? w5[co * 144 + ci * 9 + t] : 0.0f;
    }
    wp[W5F + q] = pkrtz(v[0], v[1]);
  } else if (i < WTOT) {  // dense: wd [10][216], k = ci*9 + px
    int j = i - WDF;
    int o = j / 108, r = j % 108, cp = r / 9, s = r % 9;
    wp[WDF + j] = pkrtz(wd[o * 216 + (2 * cp) * 9 + s],
                        wd[o * 216 + (2 * cp + 1) * 9 + s]);
  }
}

// ---- fused network: 1 image per 256-thread block -----------------------
// Channels-last f16 activations (u32 = ci-pair). Per image:
//  Arena A (3600): IN dual-parity f16 [2][35][20](1400) -> a2[30][30][8ci](3600)
//    -> a3[16][16][16ci](2048) -> p2[9][9][16ci](648) -> p3(108)+partials
//  Arena B (2048): a1[32][32][4ci](2048) -> p1[16][16][8ci](1024)
//    -> a4[16][16][16ci](2048) -> a5[7][7][24ci](588)
// 22.6KB LDS -> 7 blocks/CU x 4 waves = 28 waves/CU.
#define AR_A 3600
#define AR_B 2048
#define SMEMN (AR_A + AR_B)  // 5648 u32 = 22592 B

__device__ __forceinline__ f32x4 mfma16(uint4 a, uint4 b, f32x4 c) {
  return __builtin_amdgcn_mfma_f32_16x16x32_f16(
      __builtin_bit_cast(f16x8, a), __builtin_bit_cast(f16x8, b), c, 0, 0, 0);
}

__global__ void __launch_bounds__(256) mnist_fused(
    const float* __restrict__ in, const u32* __restrict__ wp,
    float* __restrict__ out) {
  __shared__ __align__(16) u32 smem[SMEMN];
  const int t = threadIdx.x;
  const int lane = t & 63;
  const int wid = t >> 6;  // 0..3
  const long long b = blockIdx.x;
  u32* SA = smem;
  u32* SB = smem + AR_A;

  // per-lane mfma identities: col n = pixel within 16-px tile
  const int s_ = lane >> 4, pxg = lane & 15;

  // P0: zero IN (both parities) + a1
  {
    uint4 z = {0, 0, 0, 0};
    uint4* za = (uint4*)SA;
    uint4* zb = (uint4*)SB;
    for (int i = t; i < 350; i += 256) za[i] = z;
    for (int i = t; i < 512; i += 256) zb[i] = z;
  }
  __syncthreads();

  // P1: stage input as f16, dual parity. H0[sy*40+sx]=v, H1[sy*40+sx-1]=v
  {
    const float* inb = in + b * 784;
    _Float16* H0 = (_Float16*)SA;
    _Float16* H1 = (_Float16*)(SA + 700);
    for (int p = t; p < 784; p += 256) {
      int y = p / 28, x = p % 28;
      _Float16 h = (_Float16)inb[p];
      int sy = y + 3, sx = x + 3;
      H0[sy * 40 + sx] = h;
      H1[sy * 40 + sx - 1] = h;
    }
  }
  __syncthreads();

  // P2: conv1 MFMA, double-tile: j=y (0..27), tiles x=pxg and x=16+pxg
  {
    uint4 af[2];
    const uint4* wq = (const uint4*)(wp + W1F);
    af[0] = wq[lane];
    af[1] = wq[64 + lane];
    #pragma unroll 1
    for (int j = wid; j < 28; j += 4) {
      int y = j;
      int x = pxg;  // tile0: x 0..15 (always valid); tile1: x+16, mask <28
      const u32* base = SA + ((x & 1) ? 700 : 0) + (x >> 1);
      f32x4 acc0 = {0.f, 0.f, 0.f, 0.f};
      f32x4 acc1 = {0.f, 0.f, 0.f, 0.f};
      #pragma unroll
      for (int g = 0; g < 2; ++g) {
        const u32* rp = base + (y + 4 * g + s_) * 20;
        uint4 b0 = {rp[0], rp[1], rp[2], rp[3]};
        uint4 b1 = {rp[8], rp[9], rp[10], rp[11]};
        acc0 = mfma16(af[g], b0, acc0);
        acc1 = mfma16(af[g], b1, acc1);
      }
      if (s_ == 0) {
        int ob = ((y + 2) * 32 + (x + 2)) * 2;
        SB[ob] = pack_relu(acc0[0], acc0[1]);
        SB[ob + 1] = pack_relu(acc0[2], acc0[3]);
        if (x + 16 < 28) {
          SB[ob + 32] = pack_relu(acc1[0], acc1[1]);
          SB[ob + 33] = pack_relu(acc1[2], acc1[3]);
        }
      }
    }
  }
  __syncthreads();

  // P3: zero a2 halo only (116 uint4: rows 0/29, cols 0/29 of [30][30]px)
  if (t < 116) {
    uint4 z = {0, 0, 0, 0};
    int idx;
    if (t < 30) idx = t;                     // row 0
    else if (t < 60) idx = 870 + (t - 30);   // row 29
    else if (t < 88) idx = (t - 59) * 30;    // col 0, rows 1..28
    else idx = (t - 87) * 30 + 29;           // col 29, rows 1..28
    ((uint4*)SA)[idx] = z;
  }
  __syncthreads();

  // P4: conv2 MFMA, double-tile. K=25taps*4ci -> 4 g
  {
    uint4 af[4];
    const uint4* wq = (const uint4*)(wp + W2F);
    #pragma unroll
    for (int g = 0; g < 4; ++g) af[g] = wq[g * 64 + lane];
    int ro0[4], ro1[4];
    #pragma unroll
    for (int g = 0; g < 4; ++g) {
      int t0 = imin(g * 8 + 2 * s_, 24), t1 = imin(g * 8 + 2 * s_ + 1, 24);
      ro0[g] = ((t0 / 5) * 32 + t0 % 5) * 2;
      ro1[g] = ((t1 / 5) * 32 + t1 % 5) * 2;
    }
    #pragma unroll 1
    for (int j = wid; j < 28; j += 4) {
      int y = j;
      int x = pxg;
      int ab = (y * 32 + x) * 2;
      f32x4 acc0 = {0.f, 0.f, 0.f, 0.f};
      f32x4 acc1 = {0.f, 0.f, 0.f, 0.f};
      #pragma unroll
      for (int g = 0; g < 4; ++g) {
        uint2 lo0 = *(const uint2*)(SB + ab + ro0[g]);
        uint2 hi0 = *(const uint2*)(SB + ab + ro1[g]);
        uint4 b0 = {lo0.x, lo0.y, hi0.x, hi0.y};
        acc0 = mfma16(af[g], b0, acc0);
        uint2 lo1 = *(const uint2*)(SB + ab + 32 + ro0[g]);
        uint2 hi1 = *(const uint2*)(SB + ab + 32 + ro1[g]);
        uint4 b1 = {lo1.x, lo1.y, hi1.x, hi1.y};
        acc1 = mfma16(af[g], b1, acc1);
      }
      if (s_ < 2) {
        int ob = ((y + 1) * 30 + (x + 1)) * 4;
        SA[ob + 2 * s_] = pack_relu(acc0[0], acc0[1]);
        SA[ob + 2 * s_ + 1] = pack_relu(acc0[2], acc0[3]);
        if (x + 16 < 28) {
          SA[ob + 64 + 2 * s_] = pack_relu(acc1[0], acc1[1]);
          SA[ob + 64 + 2 * s_ + 1] = pack_relu(acc1[2], acc1[3]);
        }
      }
    }
  }
  __syncthreads();

  // P5: zero p1
  {
    uint4 z = {0, 0, 0, 0};
    uint4* zb = (uint4*)SB;
    for (int i = t; i < 256; i += 256) zb[i] = z;
  }
  __syncthreads();

  // P6: pool1 3x3 s2 p1: a2[30][30][4] -> p1[16][16][4], uint4 units
  if (t < 196) {
    int y = t / 14, x = t % 14;
    const u32* basep = SA + ((2 * y) * 30 + 2 * x) * 4;
    u32 m0 = 0, m1 = 0, m2 = 0, m3 = 0;
    #pragma unroll
    for (int jj = 0; jj < 3; ++jj)
      #pragma unroll
      for (int kk = 0; kk < 3; ++kk) {
        uint4 v = *(const uint4*)(basep + (jj * 30 + kk) * 4);
        m0 = max2(m0, v.x);
        m1 = max2(m1, v.y);
        m2 = max2(m2, v.z);
        m3 = max2(m3, v.w);
      }
    uint4 r = {m0, m1, m2, m3};
    *(uint4*)(SB + ((y + 1) * 16 + (x + 1)) * 4) = r;
  }
  __syncthreads();

  // P7: zero a3
  {
    uint4 z = {0, 0, 0, 0};
    uint4* za = (uint4*)SA;
    for (int i = t; i < 512; i += 256) za[i] = z;
  }
  __syncthreads();

  // P8: conv3 MFMA, double-row: j=0..6, rows 2j and 2j+1, x=pxg mask<14
  {
    uint4 af[3];
    const uint4* wq = (const uint4*)(wp + W3F);
    #pragma unroll
    for (int g = 0; g < 3; ++g) af[g] = wq[g * 64 + lane];
    int roff[3];
    #pragma unroll
    for (int g = 0; g < 3; ++g) {
      int tt = imin(g * 4 + s_, 8);
      roff[g] = ((tt / 3) * 16 + tt % 3) * 4;
    }
    #pragma unroll 1
    for (int j = wid; j < 7; j += 4) {
      int y0 = 2 * j;
      int x = pxg;
      int ab = (y0 * 16 + x) * 4;  // row+1 = +64
      f32x4 acc0 = {0.f, 0.f, 0.f, 0.f};
      f32x4 acc1 = {0.f, 0.f, 0.f, 0.f};
      #pragma unroll
      for (int g = 0; g < 3; ++g) {
        uint4 b0 = *(const uint4*)(SB + ab + roff[g]);
        acc0 = mfma16(af[g], b0, acc0);
        uint4 b1 = *(const uint4*)(SB + ab + 64 + roff[g]);
        acc1 = mfma16(af[g], b1, acc1);
      }
      if (x < 14) {
        int cp0 = 2 * s_, cp1 = 2 * s_ + 1;
        int ob0 = ((y0 + 1) * 16 + (x + 1)) * 8;
        u32 p00 = pack_relu(acc0[0], acc0[1]);
        u32 p01 = pack_relu(acc0[2], acc0[3]);
        u32 p10 = pack_relu(acc1[0], acc1[1]);
        u32 p11 = pack_relu(acc1[2], acc1[3]);
        if (cp0 < 5) {
          SA[ob0 + cp0] = p00;
          SA[ob0 + 128 + cp0] = p10;
        }
        if (cp1 < 5) {
          SA[ob0 + cp1] = p01;
          SA[ob0 + 128 + cp1] = p11;
        }
      }
    }
  }
  __syncthreads();

  // P9: zero a4
  {
    uint4 z = {0, 0, 0, 0};
    uint4* zb = (uint4*)SB;
    for (int i = t; i < 512; i += 256) zb[i] = z;
  }
  __syncthreads();

  // P10: conv4 MFMA, double-row: j=0..6, rows 2j/2j+1
  {
    uint4 af[5];
    const uint4* wq = (const uint4*)(wp + W4F);
    #pragma unroll
    for (int g = 0; g < 5; ++g) af[g] = wq[g * 64 + lane];
    int roff[5];
    #pragma unroll
    for (int g = 0; g < 5; ++g) {
      int tt = imin(g * 2 + (s_ >> 1), 8);
      roff[g] = ((tt / 3) * 16 + tt % 3) * 8 + (s_ & 1) * 4;
    }
    #pragma unroll 1
    for (int j = wid; j < 7; j += 4) {
      int y0 = 2 * j;
      int x = pxg;
      int ab = (y0 * 16 + x) * 8;  // row+1 = +128
      f32x4 acc0 = {0.f, 0.f, 0.f, 0.f};
      f32x4 acc1 = {0.f, 0.f, 0.f, 0.f};
      #pragma unroll
      for (int g = 0; g < 5; ++g) {
        uint4 b0 = *(const uint4*)(SA + ab + roff[g]);
        acc0 = mfma16(af[g], b0, acc0);
        uint4 b1 = *(const uint4*)(SA + ab + 128 + roff[g]);
        acc1 = mfma16(af[g], b1, acc1);
      }
      if (x < 14) {
        int ob0 = ((y0 + 1) * 16 + (x + 1)) * 8;
        SB[ob0 + 2 * s_] = pack_relu(acc0[0], acc0[1]);
        SB[ob0 + 2 * s_ + 1] = pack_relu(acc0[2], acc0[3]);
        SB[ob0 + 128 + 2 * s_] = pack_relu(acc1[0], acc1[1]);
        SB[ob0 + 128 + 2 * s_ + 1] = pack_relu(acc1[2], acc1[3]);
      }
    }
  }
  __syncthreads();

  // P11: zero p2
  {
    uint4 z = {0, 0, 0, 0};
    uint4* za = (uint4*)SA;
    for (int i = t; i < 162; i += 256) za[i] = z;
  }
  __syncthreads();

  // P12: pool2 3x3 s2 p1: a4[16][16][8] -> p2[9][9][8], uint4 lanes
  if (t < 98) {
    int cpq = t & 1, pxq = t >> 1;
    int y = pxq / 7, x = pxq % 7;
    const u32* basep = SB + ((2 * y) * 16 + 2 * x) * 8 + cpq * 4;
    u32 m0 = 0, m1 = 0, m2 = 0, m3 = 0;
    #pragma unroll
    for (int jj = 0; jj < 3; ++jj)
      #pragma unroll
      for (int kk = 0; kk < 3; ++kk) {
        uint4 v = *(const uint4*)(basep + (jj * 16 + kk) * 8);
        m0 = max2(m0, v.x);
        m1 = max2(m1, v.y);
        m2 = max2(m2, v.z);
        m3 = max2(m3, v.w);
      }
    uint4 r = {m0, m1, m2, m3};
    *(uint4*)(SA + ((y + 1) * 9 + (x + 1)) * 8 + cpq * 4) = r;
  }
  __syncthreads();

  // P13: conv5 MFMA: j=row 0..6, shared B-reads, both co-tiles per j
  {
    int roff[5];
    #pragma unroll
    for (int g = 0; g < 5; ++g) {
      int tt = imin(g * 2 + (s_ >> 1), 8);
      roff[g] = ((tt / 3) * 9 + tt % 3) * 8 + (s_ & 1) * 4;
    }
    #pragma unroll 1
    for (int j = wid; j < 7; j += 4) {
      int y = j;
      int x = pxg;
      int ab = (y * 9 + x) * 8;
      uint4 bv[5];
      #pragma unroll
      for (int g = 0; g < 5; ++g) bv[g] = *(const uint4*)(SA + ab + roff[g]);
      #pragma unroll 1
      for (int cot = 0; cot < 2; ++cot) {
        uint4 af[5];
        const uint4* wq = (const uint4*)(wp + W5F + cot * 1280);
        #pragma unroll
        for (int g = 0; g < 5; ++g) af[g] = wq[g * 64 + lane];
        f32x4 acc = {0.f, 0.f, 0.f, 0.f};
        #pragma unroll
        for (int g = 0; g < 5; ++g) acc = mfma16(af[g], bv[g], acc);
        if (x < 7 && (cot == 0 || s_ < 2)) {
          int ob = (y * 7 + x) * 12 + cot * 8;
          SB[ob + 2 * s_] = pack_relu(acc[0], acc[1]);
          SB[ob + 2 * s_ + 1] = pack_relu(acc[2], acc[3]);
        }
      }
    }
  }
  __syncthreads();

  // P14: pool3 3x3 s2 p0: a5[7][7][12] -> p3 planar [12cp][9] at SA[0..107]
  if (t < 108) {
    int cp = t % 12, pxq = t / 12;
    int y = pxq / 3, x = pxq % 3;
    const u32* basep = SB + ((2 * y) * 7 + 2 * x) * 12 + cp;
    u32 m = 0;
    #pragma unroll
    for (int jj = 0; jj < 3; ++jj)
      #pragma unroll
      for (int kk = 0; kk < 3; ++kk) m = max2(m, basep[(jj * 7 + kk) * 12]);
    SA[cp * 9 + pxq] = m;
  }
  __syncthreads();

  // P15: dense partials: 10 outs x 12 ci-pair chunks of 9 px (wd from L2)
  if (t < 120) {
    int o = t / 12, c = t % 12;
    const u32* wrow = wp + WDF + o * 108 + c * 9;
    float acc = 0.f;
    #pragma unroll
    for (int s = 0; s < 9; ++s) acc = dot2(SA[c * 9 + s], wrow[s], acc);
    ((float*)SA)[128 + o * 12 + c] = acc;
  }
  __syncthreads();
  if (t < 10) {
    const float* par = (const float*)SA + 128 + t * 12;
    float s = 0.f;
    #pragma unroll
    for (int c = 0; c < 12; ++c) s += par[c];
    out[b * 10 + t] = s;
  }
}

extern "C" void kernel_launch(void* const* d_in, const int* in_sizes, int n_in,
                              void* d_out, int out_size, void* d_ws, size_t ws_size,
                              hipStream_t stream) {
  const float* in = (const float*)d_in[0];
  const float* w1 = (const float*)d_in[1];
  const float* w2 = (const float*)d_in[2];
  const float* w3 = (const float*)d_in[3];
  const float* w4 = (const float*)d_in[4];
  const float* w5 = (const float*)d_in[5];
  const float* wd = (const float*)d_in[6];
  u32* wp = (u32*)d_ws;
  float* out = (float*)d_out;
  int B = in_sizes[0] / 784;

  prep_weights<<<(WTOT + 255) / 256, 256, 0, stream>>>(w1, w2, w3, w4, w5, wd, wp);
  mnist_fused<<<B, 256, 0, stream>>>(in, wp, out);
}